// Round 1
// baseline (467.958 us; speedup 1.0000x reference)
//
#include <hip/hip_runtime.h>
#include <hip/hip_bf16.h>

// CrossAttention: b=4, n=1024, qs=256, heads=8, dim_head=64, bottleneck=40.
// Attention = full 8192x8192 softmax-attention per batch over D=64.
//
// R14:
//  - qkv: one projection per block (grid 768). LDS ~49KB -> 2 blocks/CU =
//    32 waves/CU (was 1 block/CU @93KB). Single stage-2 pass (was 3
//    serialized). Stage-1 k-split x4. Write phases copied verbatim.
//  - attn: K-fragment register double-buffer (+16 VGPR, stays under the
//    3-wave/SIMD 170-reg cap: 148+16=164) + s_setprio(1) around MFMA
//    clusters. V stays single-buffered (first use is ~200cy after issue).
//  - out: thread tile 2rx4c -> 4rx4c @ 256 threads. Halves per-CU wot
//    ds_read_b128 count (LDS-pipe floor 13.7us -> ~7us).
//
// Workspace: Q 4MB | K_sw 4MB | V_sw 4MB | Opart 2x8MB | psum 2x128KB ~ 28.3MB.

#define B_    4
#define H_    8
#define NSEQ  1024
#define SEQ   8192        // H_*NSEQ
#define DH    64
#define QS    256
#define INNER 512
#define QSCALE 0.18033688011112042f   // (1/sqrt(64)) * log2(e)

#define KVSW_BATCH 524288             // elems per batch in K_sw / V_sw

typedef __bf16 bf16x8 __attribute__((ext_vector_type(8)));
typedef float floatx4 __attribute__((ext_vector_type(4)));

// ---------------- kernel 1: QKV projections + fragment-order swizzle ----------------
// grid 768 (p*256 + b*64 + nblk), 1024 threads, 16 x-rows per block, ONE
// projection per block. LDS ~49KB -> 2 blocks/CU resident (32 waves/CU).
__global__ __launch_bounds__(1024, 8) void qkv_kernel(
    const float* __restrict__ x,
    const float* __restrict__ wq1, const float* __restrict__ wq2,
    const float* __restrict__ wk1, const float* __restrict__ wk2,
    const float* __restrict__ wv1, const float* __restrict__ wv2,
    __hip_bfloat16* __restrict__ Qg, __hip_bfloat16* __restrict__ KSg,
    __hip_bfloat16* __restrict__ VSg)
{
  const int tid  = threadIdx.x;
  const int p    = blockIdx.x >> 8;        // 0=Q 1=K 2=V
  const int rest = blockIdx.x & 255;
  const int b    = rest >> 6;
  const int nblk = rest & 63;
  const int n0   = nblk << 4;

  __shared__ __align__(16) float xs[16][260];
  __shared__ __align__(16) float tb2[4][16][40];   // k-split partials
  __shared__ __align__(16) float tb[16][40];
  // union buffer: q/k view [16][520] bf16 (8320), v view [512][20] (10240)
  __shared__ __align__(16) __hip_bfloat16 ob[10400];

  const float* w1 = (p == 0) ? wq1 : (p == 1) ? wk1 : wv1;
  const float* w2 = (p == 0) ? wq2 : (p == 1) ? wk2 : wv2;

  // stage x tile: 1024 float4 tasks, one per thread
  {
    const int r  = tid >> 6;
    const int c4 = (tid & 63) << 2;
    *(float4*)(&xs[r][c4]) =
        *(const float4*)(x + ((size_t)b * NSEQ + n0 + r) * QS + c4);
  }
  __syncthreads();

  // stage 1a: bottleneck partials, k-split x4. 640 tasks.
  if (tid < 640) {
    const int ks  = tid / 160;
    const int rem = tid - ks * 160;
    const int r   = rem / 10;
    const int bn  = (rem - r * 10) * 4;
    float a0 = 0.f, a1 = 0.f, a2 = 0.f, a3 = 0.f;
    #pragma unroll 4
    for (int c4 = ks * 16; c4 < ks * 16 + 16; ++c4) {
      const float4 xv = *(const float4*)(&xs[r][c4 * 4]);
      const float4 wa = *(const float4*)(w1 + (c4 * 4 + 0) * 40 + bn);
      const float4 wb = *(const float4*)(w1 + (c4 * 4 + 1) * 40 + bn);
      const float4 wc = *(const float4*)(w1 + (c4 * 4 + 2) * 40 + bn);
      const float4 wd = *(const float4*)(w1 + (c4 * 4 + 3) * 40 + bn);
      a0 += xv.x * wa.x + xv.y * wb.x + xv.z * wc.x + xv.w * wd.x;
      a1 += xv.x * wa.y + xv.y * wb.y + xv.z * wc.y + xv.w * wd.y;
      a2 += xv.x * wa.z + xv.y * wb.z + xv.z * wc.z + xv.w * wd.z;
      a3 += xv.x * wa.w + xv.y * wb.w + xv.z * wc.w + xv.w * wd.w;
    }
    tb2[ks][r][bn + 0] = a0; tb2[ks][r][bn + 1] = a1;
    tb2[ks][r][bn + 2] = a2; tb2[ks][r][bn + 3] = a3;
  }
  __syncthreads();

  // stage 1b: combine quarters + SiLU on K path.
  if (tid < 160) {
    const int r  = tid / 10;
    const int bn = (tid - r * 10) * 4;
    const float4 h0 = *(const float4*)(&tb2[0][r][bn]);
    const float4 h1 = *(const float4*)(&tb2[1][r][bn]);
    const float4 h2 = *(const float4*)(&tb2[2][r][bn]);
    const float4 h3 = *(const float4*)(&tb2[3][r][bn]);
    float a0 = (h0.x + h1.x) + (h2.x + h3.x);
    float a1 = (h0.y + h1.y) + (h2.y + h3.y);
    float a2 = (h0.z + h1.z) + (h2.z + h3.z);
    float a3 = (h0.w + h1.w) + (h2.w + h3.w);
    if (p == 1) {
      a0 = a0 / (1.f + __expf(-a0));
      a1 = a1 / (1.f + __expf(-a1));
      a2 = a2 / (1.f + __expf(-a2));
      a3 = a3 / (1.f + __expf(-a3));
    }
    tb[r][bn + 0] = a0; tb[r][bn + 1] = a1;
    tb[r][bn + 2] = a2; tb[r][bn + 3] = a3;
  }
  __syncthreads();

  // stage 2: 40 -> 512, single pass. thread = 2 rows x 4 cols.
  {
    const int cq = tid & 127;
    const int rq = (tid >> 7) & 7;
    const int c  = cq * 4, r0 = rq * 2;
    const float scale = (p == 0) ? QSCALE : 1.0f;
    float acc[2][4];
    #pragma unroll
    for (int i = 0; i < 2; ++i)
      #pragma unroll
      for (int j = 0; j < 4; ++j) acc[i][j] = 0.f;

    #pragma unroll 2
    for (int jb = 0; jb < 10; ++jb) {
      const float4 w0  = *(const float4*)(w2 + (jb * 4 + 0) * INNER + c);
      const float4 w1r = *(const float4*)(w2 + (jb * 4 + 1) * INNER + c);
      const float4 w2r = *(const float4*)(w2 + (jb * 4 + 2) * INNER + c);
      const float4 w3  = *(const float4*)(w2 + (jb * 4 + 3) * INNER + c);
      #pragma unroll
      for (int ri = 0; ri < 2; ++ri) {
        const float4 tv = *(const float4*)(&tb[r0 + ri][jb * 4]);
        acc[ri][0] += tv.x * w0.x + tv.y * w1r.x + tv.z * w2r.x + tv.w * w3.x;
        acc[ri][1] += tv.x * w0.y + tv.y * w1r.y + tv.z * w2r.y + tv.w * w3.y;
        acc[ri][2] += tv.x * w0.z + tv.y * w1r.z + tv.z * w2r.z + tv.w * w3.z;
        acc[ri][3] += tv.x * w0.w + tv.y * w1r.w + tv.z * w2r.w + tv.w * w3.w;
      }
    }
    #pragma unroll
    for (int ri = 0; ri < 2; ++ri)
      #pragma unroll
      for (int ci = 0; ci < 4; ++ci) {
        const int cc = c + ci;
        const float v = acc[ri][ci] * scale;
        if (p == 2) ob[cc * 20 + r0 + ri]   = __float2bfloat16(v);   // vb[cc][r]
        else        ob[(r0 + ri) * 520 + cc] = __float2bfloat16(v);  // qb/kb[r][cc]
      }
  }
  __syncthreads();

  if (p == 0) {
    // ---- Q write: 1024 float4 tasks ----
    const int i  = tid;
    const int h  = i >> 7;
    const int r  = (i >> 3) & 15;
    const int d8 = i & 7;
    *(float4*)(Qg + ((size_t)b * SEQ + h * NSEQ + n0 + r) * DH + d8 * 8) =
        *(const float4*)(&ob[r * 520 + h * 64 + d8 * 8]);
  } else if (p == 1) {
    // ---- K_sw write: 1024 float4 tasks (t16 = h*64+nblk) ----
    const int i    = tid;
    const int h    = i >> 7;
    const int ks2  = (i >> 6) & 1;
    const int quad = (i >> 4) & 3;
    const int r    = i & 15;
    const int lane = quad * 16 + r;
    const size_t dst = (size_t)b * KVSW_BATCH
        + ((size_t)((h * 64 + nblk) * 2 + ks2) * 64 + lane) * 8;
    *(float4*)(KSg + dst) = *(const float4*)(&ob[r * 520 + h * 64 + ks2 * 32 + quad * 8]);
  } else {
    // ---- V_sw write: 2048 uint2 tasks ----
    const int st  = nblk & 1;
    const int p32 = nblk >> 1;
    #pragma unroll
    for (int pass = 0; pass < 2; ++pass) {
      const int i   = tid + pass * 1024;
      const int h   = i >> 8;
      const int dnt = (i >> 6) & 3;
      const int dm  = (i >> 2) & 15;
      const int rg  = i & 3;
      const int lane = rg * 16 + dm;
      const size_t dst = (size_t)b * KVSW_BATCH
          + ((size_t)((h * 32 + p32) * 4 + dnt) * 64 + lane) * 8 + st * 4;
      *(uint2*)(VSg + dst) = *(const uint2*)(&ob[(h * 64 + dnt * 16 + dm) * 20 + rg * 4]);
    }
  }
}

// ---------------- kernel 2: attention, kv-split partial blocks ----------------
// R14: K-fragment register double-buffer + setprio around MFMA clusters.
__global__ __launch_bounds__(256, 3) void attn_kernel(
    const __hip_bfloat16* __restrict__ Qg,
    const __hip_bfloat16* __restrict__ KSg,
    const __hip_bfloat16* __restrict__ VSg,
    float* __restrict__ OPg,       // [2][B_][SEQ][DH]
    float* __restrict__ PSg)       // [2][B_][SEQ]
{
  __shared__ float Osh[4][16][68];
  __shared__ float psums[4][64];

  const int tid  = threadIdx.x;
  const int wave = tid >> 6;
  const int lane = tid & 63;
  const int lrow = lane & 15;
  const int quad = lane >> 4;

  const int xcd   = blockIdx.x & 7;
  const int idx   = blockIdx.x >> 3;       // [0,128)
  const int b     = xcd >> 1;
  const int half  = idx & 1;
  const int qtile = (xcd & 1) * 64 + (idx >> 1);
  const int qbase = qtile * 64;

  const __hip_bfloat16* Qb  = Qg + ((size_t)b * SEQ + qbase) * DH;
  const __hip_bfloat16* kp0 = KSg + (size_t)b * KVSW_BATCH + half * 262144
                              + (size_t)wave * 65536 + lane * 8;
  const __hip_bfloat16* vp0 = VSg + (size_t)b * KVSW_BATCH + half * 262144
                              + (size_t)wave * 65536 + lane * 8;

  bf16x8 qf[4][2];
  #pragma unroll
  for (int mt = 0; mt < 4; ++mt)
    #pragma unroll
    for (int s = 0; s < 2; ++s)
      qf[mt][s] = *(const bf16x8*)(Qb + (mt * 16 + lrow) * DH + s * 32 + quad * 8);

  floatx4 oacc[4][4];   // [mt][dnt] — 64 acc regs (unified budget)
  #pragma unroll
  for (int mt = 0; mt < 4; ++mt)
    #pragma unroll
    for (int dnt = 0; dnt < 4; ++dnt)
      oacc[mt][dnt] = (floatx4){0.f, 0.f, 0.f, 0.f};
  float psum[4] = {0.f, 0.f, 0.f, 0.f};

  auto LOADK = [&](bf16x8 (&k)[2][2], int pr) {
    const __hip_bfloat16* kp = kp0 + (size_t)pr * 2048;
    k[0][0] = *(const bf16x8*)(kp);
    k[0][1] = *(const bf16x8*)(kp + 512);
    k[1][0] = *(const bf16x8*)(kp + 1024);
    k[1][1] = *(const bf16x8*)(kp + 1536);
  };

  auto COMPUTE = [&](const bf16x8 (&k)[2][2], int pr) {
    const __hip_bfloat16* vp = vp0 + (size_t)pr * 2048;
    bf16x8 v[4];
    #pragma unroll
    for (int dnt = 0; dnt < 4; ++dnt)
      v[dnt] = *(const bf16x8*)(vp + dnt * 512);

    #pragma unroll
    for (int mt = 0; mt < 4; ++mt) {
      floatx4 s0 = (floatx4){0.f, 0.f, 0.f, 0.f};
      floatx4 s1 = (floatx4){0.f, 0.f, 0.f, 0.f};
      __builtin_amdgcn_s_setprio(1);
      s0 = __builtin_amdgcn_mfma_f32_16x16x32_bf16(k[0][0], qf[mt][0], s0, 0, 0, 0);
      s0 = __builtin_amdgcn_mfma_f32_16x16x32_bf16(k[0][1], qf[mt][1], s0, 0, 0, 0);
      s1 = __builtin_amdgcn_mfma_f32_16x16x32_bf16(k[1][0], qf[mt][0], s1, 0, 0, 0);
      s1 = __builtin_amdgcn_mfma_f32_16x16x32_bf16(k[1][1], qf[mt][1], s1, 0, 0, 0);
      __builtin_amdgcn_s_setprio(0);
      float p[8];
      #pragma unroll
      for (int r = 0; r < 4; ++r) {
        p[r]     = __builtin_amdgcn_exp2f(s0[r]);
        p[4 + r] = __builtin_amdgcn_exp2f(s1[r]);
      }
      psum[mt] += ((p[0] + p[1]) + (p[2] + p[3])) + ((p[4] + p[5]) + (p[6] + p[7]));
      bf16x8 pa;
      #pragma unroll
      for (int j = 0; j < 8; ++j) pa[j] = (__bf16)p[j];
      __builtin_amdgcn_s_setprio(1);
      #pragma unroll
      for (int dnt = 0; dnt < 4; ++dnt)
        oacc[mt][dnt] = __builtin_amdgcn_mfma_f32_16x16x32_bf16(pa, v[dnt], oacc[mt][dnt], 0, 0, 0);
      __builtin_amdgcn_s_setprio(0);
    }
  };

  bf16x8 kA[2][2], kB[2][2];
  LOADK(kA, 0);
  #pragma unroll 1
  for (int pair = 0; pair < 32; pair += 2) {
    LOADK(kB, pair + 1);
    COMPUTE(kA, pair);
    LOADK(kA, (pair + 2) & 31);
    COMPUTE(kB, pair + 1);
  }

  #pragma unroll
  for (int mt = 0; mt < 4; ++mt) {
    float s = psum[mt];
    s += __shfl_xor(s, 16, 64);
    s += __shfl_xor(s, 32, 64);
    psum[mt] = s;
  }
  if (quad == 0) {
    #pragma unroll
    for (int mt = 0; mt < 4; ++mt)
      psums[wave][mt * 16 + lrow] = psum[mt];
  }

  const size_t opbase = ((size_t)half * B_ + b) * SEQ + qbase;

  #pragma unroll
  for (int mt = 0; mt < 4; ++mt) {
    #pragma unroll
    for (int dnt = 0; dnt < 4; ++dnt)
      #pragma unroll
      for (int r = 0; r < 4; ++r)
        Osh[wave][quad * 4 + r][dnt * 16 + lrow] = oacc[mt][dnt][r];
    __syncthreads();

    {
      const int q16 = tid >> 4;
      const int d0  = (tid & 15) * 4;
      float4 a0 = *(const float4*)(&Osh[0][q16][d0]);
      float4 a1 = *(const float4*)(&Osh[1][q16][d0]);
      float4 a2 = *(const float4*)(&Osh[2][q16][d0]);
      float4 a3 = *(const float4*)(&Osh[3][q16][d0]);
      float4 res;
      res.x = (a0.x + a1.x) + (a2.x + a3.x);
      res.y = (a0.y + a1.y) + (a2.y + a3.y);
      res.z = (a0.z + a1.z) + (a2.z + a3.z);
      res.w = (a0.w + a1.w) + (a2.w + a3.w);
      *(float4*)(OPg + (opbase + mt * 16 + q16) * DH + d0) = res;
    }
    if (mt == 0 && tid < 64) {
      const float tot = (psums[0][tid] + psums[1][tid]) + (psums[2][tid] + psums[3][tid]);
      PSg[opbase + tid] = tot;
    }
    __syncthreads();
  }
}

// ---------------- kernel 3: out = merge(Opart)/denom @ wo + bo ----------------
// grid 256 (1 block/CU), 256 threads. 16 rows x 256 cols. wo staged through
// LDS in K-tiles of 16 (reg-prefetch double buffer, one barrier per tile).
// R14: thread = 4 rows x 4 cols -> halves per-CU wot ds_read count.
__global__ __launch_bounds__(256) void out_kernel(
    const float* __restrict__ OPg, const float* __restrict__ PSg,
    const float* __restrict__ wo, const float* __restrict__ bo,
    float* __restrict__ out)
{
  const int tid = threadIdx.x;
  const int b   = blockIdx.x >> 6;
  const int n0  = (blockIdx.x & 63) << 4;

  __shared__ __align__(16) float os[16][520];
  __shared__ __align__(16) float wot[2][16][260];
  __shared__ float invs[16][8];

  if (tid < 128) {
    const int r = tid >> 3, h = tid & 7;
    const size_t row = (size_t)b * SEQ + h * NSEQ + n0 + r;
    invs[r][h] = 1.0f / (PSg[row] + PSg[(size_t)B_ * SEQ + row]);
  }
  __syncthreads();

  // gather + merge halves + normalize -> os (2048 float4 tasks, 8/thread)
  for (int i = tid; i < 2048; i += 256) {
    const int r  = i >> 7;
    const int c4 = (i & 127) * 4;
    const int h  = c4 >> 6;
    const size_t idx = ((size_t)b * SEQ + h * NSEQ + n0 + r) * DH + (c4 & 63);
    const float4 p0 = *(const float4*)(OPg + idx);
    const float4 p1 = *(const float4*)(OPg + (size_t)B_ * SEQ * DH + idx);
    const float inv = invs[r][h];
    float4 m;
    m.x = (p0.x + p1.x) * inv;
    m.y = (p0.y + p1.y) * inv;
    m.z = (p0.z + p1.z) * inv;
    m.w = (p0.w + p1.w) * inv;
    *(float4*)(&os[r][c4]) = m;
  }

  // stage tile 0 of wo (1024 float4 chunks: krow = c>>6, col = (c&63)*4)
  {
    #pragma unroll
    for (int j = 0; j < 4; ++j) {
      const int cc = tid + j * 256;
      *(float4*)(&wot[0][cc >> 6][(cc & 63) * 4]) =
          *(const float4*)(wo + (size_t)(cc >> 6) * QS + (cc & 63) * 4);
    }
  }
  __syncthreads();

  const int oq = tid & 63;      // col group: o = oq*4
  const int rg = tid >> 6;      // row group: rows rg*4 .. rg*4+3
  const int o  = oq * 4;
  const int r0 = rg * 4;

  float acc[4][4];
  #pragma unroll
  for (int i = 0; i < 4; ++i)
    #pragma unroll
    for (int j = 0; j < 4; ++j) acc[i][j] = 0.f;

  for (int kt = 0; kt < 32; ++kt) {
    const int cur = kt & 1;
    // prefetch next tile into registers (latency hidden by compute below)
    float4 pf0, pf1, pf2, pf3;
    if (kt < 31) {
      const int kb = (kt + 1) * 16;
      const int c0 = tid, c1 = tid + 256, c2 = tid + 512, c3 = tid + 768;
      pf0 = *(const float4*)(wo + (size_t)(kb + (c0 >> 6)) * QS + (c0 & 63) * 4);
      pf1 = *(const float4*)(wo + (size_t)(kb + (c1 >> 6)) * QS + (c1 & 63) * 4);
      pf2 = *(const float4*)(wo + (size_t)(kb + (c2 >> 6)) * QS + (c2 & 63) * 4);
      pf3 = *(const float4*)(wo + (size_t)(kb + (c3 >> 6)) * QS + (c3 & 63) * 4);
    }

    // compute this tile
    const int kbase = kt * 16;
    #pragma unroll
    for (int kq = 0; kq < 4; ++kq) {
      const float4 ov0 = *(const float4*)(&os[r0 + 0][kbase + kq * 4]);   // broadcast
      const float4 ov1 = *(const float4*)(&os[r0 + 1][kbase + kq * 4]);   // broadcast
      const float4 ov2 = *(const float4*)(&os[r0 + 2][kbase + kq * 4]);   // broadcast
      const float4 ov3 = *(const float4*)(&os[r0 + 3][kbase + kq * 4]);   // broadcast
      #pragma unroll
      for (int j = 0; j < 4; ++j) {
        const float4 w = *(const float4*)(&wot[cur][kq * 4 + j][o]);
        const float a0 = (j == 0) ? ov0.x : (j == 1) ? ov0.y : (j == 2) ? ov0.z : ov0.w;
        const float a1 = (j == 0) ? ov1.x : (j == 1) ? ov1.y : (j == 2) ? ov1.z : ov1.w;
        const float a2 = (j == 0) ? ov2.x : (j == 1) ? ov2.y : (j == 2) ? ov2.z : ov2.w;
        const float a3 = (j == 0) ? ov3.x : (j == 1) ? ov3.y : (j == 2) ? ov3.z : ov3.w;
        acc[0][0] += a0 * w.x; acc[0][1] += a0 * w.y; acc[0][2] += a0 * w.z; acc[0][3] += a0 * w.w;
        acc[1][0] += a1 * w.x; acc[1][1] += a1 * w.y; acc[1][2] += a1 * w.z; acc[1][3] += a1 * w.w;
        acc[2][0] += a2 * w.x; acc[2][1] += a2 * w.y; acc[2][2] += a2 * w.z; acc[2][3] += a2 * w.w;
        acc[3][0] += a3 * w.x; acc[3][1] += a3 * w.y; acc[3][2] += a3 * w.z; acc[3][3] += a3 * w.w;
      }
    }

    if (kt < 31) {
      const int c0 = tid, c1 = tid + 256, c2 = tid + 512, c3 = tid + 768;
      *(float4*)(&wot[cur ^ 1][c0 >> 6][(c0 & 63) * 4]) = pf0;
      *(float4*)(&wot[cur ^ 1][c1 >> 6][(c1 & 63) * 4]) = pf1;
      *(float4*)(&wot[cur ^ 1][c2 >> 6][(c2 & 63) * 4]) = pf2;
      *(float4*)(&wot[cur ^ 1][c3 >> 6][(c3 & 63) * 4]) = pf3;
    }
    __syncthreads();
  }

  const float4 bv = *(const float4*)(bo + o);
  #pragma unroll
  for (int ri = 0; ri < 4; ++ri) {
    float4 res;
    res.x = acc[ri][0] + bv.x;
    res.y = acc[ri][1] + bv.y;
    res.z = acc[ri][2] + bv.z;
    res.w = acc[ri][3] + bv.w;
    *(float4*)(out + ((size_t)b * NSEQ + n0 + r0 + ri) * QS + o) = res;
  }
}

extern "C" void kernel_launch(void* const* d_in, const int* in_sizes, int n_in,
                              void* d_out, int out_size, void* d_ws, size_t ws_size,
                              hipStream_t stream) {
  const float* x   = (const float*)d_in[0];
  const float* wq1 = (const float*)d_in[1];
  const float* wq2 = (const float*)d_in[2];
  const float* wk1 = (const float*)d_in[3];
  const float* wk2 = (const float*)d_in[4];
  const float* wv1 = (const float*)d_in[5];
  const float* wv2 = (const float*)d_in[6];
  const float* wo  = (const float*)d_in[7];
  const float* bo  = (const float*)d_in[8];
  float* out = (float*)d_out;

  __hip_bfloat16* Qg  = (__hip_bfloat16*)d_ws;
  __hip_bfloat16* KSg = Qg + (size_t)B_ * SEQ * DH;
  __hip_bfloat16* VSg = KSg + (size_t)B_ * KVSW_BATCH;
  float*          OPg = (float*)(VSg + (size_t)B_ * KVSW_BATCH);   // [2][B_][SEQ][DH]
  float*          PSg = OPg + 2 * (size_t)B_ * SEQ * DH;           // [2][B_][SEQ]

  qkv_kernel<<<768, 1024, 0, stream>>>(x, wq1, wq2, wk1, wk2, wv1, wv2, Qg, KSg, VSg);
  attn_kernel<<<1024, 256, 0, stream>>>(Qg, KSg, VSg, OPg, PSg);
  out_kernel<<<256, 256, 0, stream>>>(OPg, PSg, wo, bo, out);
}

// Round 2
// 191.929 us; speedup vs baseline: 2.4382x; 2.4382x over previous
//
#include <hip/hip_runtime.h>
#include <hip/hip_bf16.h>

// CrossAttention: b=4, n=1024, qs=256, heads=8, dim_head=64, bottleneck=40.
// Attention = full 8192x8192 softmax-attention per batch over D=64.
//
// R15:
//  - attn: EXACT revert to R13 frozen version (73.3us). R14's K-reg
//    double-buffer caused scratch spills (WRITE_SIZE 16MB->731MB, 344us).
//  - out: EXACT revert to R13 512-thread version (8 waves/CU).
//  - qkv (the one experimental variable): one projection per block
//    (grid 768) at 512 threads, launch_bounds(512,4) -> 2 blocks/CU
//    (LDS 2x49KB), 16 waves/CU, VGPR cap 128 (no spill). Single stage-2
//    pass. Tests "qkv is latency-bound" with safe occupancy.
//
// Workspace: Q 4MB | K_sw 4MB | V_sw 4MB | Opart 2x8MB | psum 2x128KB ~ 28.3MB.

#define B_    4
#define H_    8
#define NSEQ  1024
#define SEQ   8192        // H_*NSEQ
#define DH    64
#define QS    256
#define INNER 512
#define QSCALE 0.18033688011112042f   // (1/sqrt(64)) * log2(e)

#define KVSW_BATCH 524288             // elems per batch in K_sw / V_sw

typedef __bf16 bf16x8 __attribute__((ext_vector_type(8)));
typedef float floatx4 __attribute__((ext_vector_type(4)));

// ---------------- kernel 1: QKV projections + fragment-order swizzle ----------------
// grid 768 (p*256 + b*64 + nblk), 512 threads, 16 x-rows per block, ONE
// projection per block. LDS ~49KB -> 2 blocks/CU resident (16 waves/CU).
__global__ __launch_bounds__(512, 4) void qkv_kernel(
    const float* __restrict__ x,
    const float* __restrict__ wq1, const float* __restrict__ wq2,
    const float* __restrict__ wk1, const float* __restrict__ wk2,
    const float* __restrict__ wv1, const float* __restrict__ wv2,
    __hip_bfloat16* __restrict__ Qg, __hip_bfloat16* __restrict__ KSg,
    __hip_bfloat16* __restrict__ VSg)
{
  const int tid  = threadIdx.x;
  const int p    = blockIdx.x >> 8;        // 0=Q 1=K 2=V
  const int rest = blockIdx.x & 255;
  const int b    = rest >> 6;
  const int nblk = rest & 63;
  const int n0   = nblk << 4;

  __shared__ __align__(16) float xs[16][260];
  __shared__ __align__(16) float tb2[4][16][40];   // k-split partials
  __shared__ __align__(16) float tb[16][40];
  // union buffer: q/k view [16][520] bf16 (8320), v view [512][20] (10240)
  __shared__ __align__(16) __hip_bfloat16 ob[10400];

  const float* w1 = (p == 0) ? wq1 : (p == 1) ? wk1 : wv1;
  const float* w2 = (p == 0) ? wq2 : (p == 1) ? wk2 : wv2;

  // stage x tile: 1024 float4 tasks, 2 per thread
  #pragma unroll
  for (int j = 0; j < 2; ++j) {
    const int i  = tid + j * 512;
    const int r  = i >> 6;
    const int c4 = (i & 63) << 2;
    *(float4*)(&xs[r][c4]) =
        *(const float4*)(x + ((size_t)b * NSEQ + n0 + r) * QS + c4);
  }
  __syncthreads();

  // stage 1a: bottleneck partials, k-split x4. 640 tasks (1-2 per thread).
  for (int t = tid; t < 640; t += 512) {
    const int ks  = t / 160;
    const int rem = t - ks * 160;
    const int r   = rem / 10;
    const int bn  = (rem - r * 10) * 4;
    float a0 = 0.f, a1 = 0.f, a2 = 0.f, a3 = 0.f;
    #pragma unroll 4
    for (int c4 = ks * 16; c4 < ks * 16 + 16; ++c4) {
      const float4 xv = *(const float4*)(&xs[r][c4 * 4]);
      const float4 wa = *(const float4*)(w1 + (c4 * 4 + 0) * 40 + bn);
      const float4 wb = *(const float4*)(w1 + (c4 * 4 + 1) * 40 + bn);
      const float4 wc = *(const float4*)(w1 + (c4 * 4 + 2) * 40 + bn);
      const float4 wd = *(const float4*)(w1 + (c4 * 4 + 3) * 40 + bn);
      a0 += xv.x * wa.x + xv.y * wb.x + xv.z * wc.x + xv.w * wd.x;
      a1 += xv.x * wa.y + xv.y * wb.y + xv.z * wc.y + xv.w * wd.y;
      a2 += xv.x * wa.z + xv.y * wb.z + xv.z * wc.z + xv.w * wd.z;
      a3 += xv.x * wa.w + xv.y * wb.w + xv.z * wc.w + xv.w * wd.w;
    }
    tb2[ks][r][bn + 0] = a0; tb2[ks][r][bn + 1] = a1;
    tb2[ks][r][bn + 2] = a2; tb2[ks][r][bn + 3] = a3;
  }
  __syncthreads();

  // stage 1b: combine quarters + SiLU on K path.
  if (tid < 160) {
    const int r  = tid / 10;
    const int bn = (tid - r * 10) * 4;
    const float4 h0 = *(const float4*)(&tb2[0][r][bn]);
    const float4 h1 = *(const float4*)(&tb2[1][r][bn]);
    const float4 h2 = *(const float4*)(&tb2[2][r][bn]);
    const float4 h3 = *(const float4*)(&tb2[3][r][bn]);
    float a0 = (h0.x + h1.x) + (h2.x + h3.x);
    float a1 = (h0.y + h1.y) + (h2.y + h3.y);
    float a2 = (h0.z + h1.z) + (h2.z + h3.z);
    float a3 = (h0.w + h1.w) + (h2.w + h3.w);
    if (p == 1) {
      a0 = a0 / (1.f + __expf(-a0));
      a1 = a1 / (1.f + __expf(-a1));
      a2 = a2 / (1.f + __expf(-a2));
      a3 = a3 / (1.f + __expf(-a3));
    }
    tb[r][bn + 0] = a0; tb[r][bn + 1] = a1;
    tb[r][bn + 2] = a2; tb[r][bn + 3] = a3;
  }
  __syncthreads();

  // stage 2: 40 -> 512, single pass. thread = 4 rows x 4 cols.
  {
    const int cq = tid & 127;
    const int rq = tid >> 7;            // [0,4)
    const int c  = cq * 4, r0 = rq * 4;
    const float scale = (p == 0) ? QSCALE : 1.0f;
    float acc[4][4];
    #pragma unroll
    for (int i = 0; i < 4; ++i)
      #pragma unroll
      for (int j = 0; j < 4; ++j) acc[i][j] = 0.f;

    #pragma unroll 2
    for (int jb = 0; jb < 10; ++jb) {
      const float4 w0  = *(const float4*)(w2 + (jb * 4 + 0) * INNER + c);
      const float4 w1r = *(const float4*)(w2 + (jb * 4 + 1) * INNER + c);
      const float4 w2r = *(const float4*)(w2 + (jb * 4 + 2) * INNER + c);
      const float4 w3  = *(const float4*)(w2 + (jb * 4 + 3) * INNER + c);
      #pragma unroll
      for (int ri = 0; ri < 4; ++ri) {
        const float4 tv = *(const float4*)(&tb[r0 + ri][jb * 4]);   // wave-broadcast
        acc[ri][0] += tv.x * w0.x + tv.y * w1r.x + tv.z * w2r.x + tv.w * w3.x;
        acc[ri][1] += tv.x * w0.y + tv.y * w1r.y + tv.z * w2r.y + tv.w * w3.y;
        acc[ri][2] += tv.x * w0.z + tv.y * w1r.z + tv.z * w2r.z + tv.w * w3.z;
        acc[ri][3] += tv.x * w0.w + tv.y * w1r.w + tv.z * w2r.w + tv.w * w3.w;
      }
    }
    #pragma unroll
    for (int ri = 0; ri < 4; ++ri)
      #pragma unroll
      for (int ci = 0; ci < 4; ++ci) {
        const int cc = c + ci;
        const float v = acc[ri][ci] * scale;
        if (p == 2) ob[cc * 20 + r0 + ri]    = __float2bfloat16(v);   // vb[cc][r]
        else        ob[(r0 + ri) * 520 + cc] = __float2bfloat16(v);   // qb/kb[r][cc]
      }
  }
  __syncthreads();

  if (p == 0) {
    // ---- Q write: 1024 float4 tasks, 2 per thread ----
    #pragma unroll
    for (int j = 0; j < 2; ++j) {
      const int i  = tid + j * 512;
      const int h  = i >> 7;
      const int r  = (i >> 3) & 15;
      const int d8 = i & 7;
      *(float4*)(Qg + ((size_t)b * SEQ + h * NSEQ + n0 + r) * DH + d8 * 8) =
          *(const float4*)(&ob[r * 520 + h * 64 + d8 * 8]);
    }
  } else if (p == 1) {
    // ---- K_sw write: 1024 float4 tasks (t16 = h*64+nblk), 2 per thread ----
    #pragma unroll
    for (int j = 0; j < 2; ++j) {
      const int i    = tid + j * 512;
      const int h    = i >> 7;
      const int ks2  = (i >> 6) & 1;
      const int quad = (i >> 4) & 3;
      const int r    = i & 15;
      const int lane = quad * 16 + r;
      const size_t dst = (size_t)b * KVSW_BATCH
          + ((size_t)((h * 64 + nblk) * 2 + ks2) * 64 + lane) * 8;
      *(float4*)(KSg + dst) = *(const float4*)(&ob[r * 520 + h * 64 + ks2 * 32 + quad * 8]);
    }
  } else {
    // ---- V_sw write: 2048 uint2 tasks, 4 per thread ----
    const int st  = nblk & 1;
    const int p32 = nblk >> 1;
    #pragma unroll
    for (int pass = 0; pass < 4; ++pass) {
      const int i   = tid + pass * 512;
      const int h   = i >> 8;
      const int dnt = (i >> 6) & 3;
      const int dm  = (i >> 2) & 15;
      const int rg  = i & 3;
      const int lane = rg * 16 + dm;
      const size_t dst = (size_t)b * KVSW_BATCH
          + ((size_t)((h * 32 + p32) * 4 + dnt) * 64 + lane) * 8 + st * 4;
      *(uint2*)(VSg + dst) = *(const uint2*)(&ob[(h * 64 + dnt * 16 + dm) * 20 + rg * 4]);
    }
  }
}

// ---------------- kernel 2: attention, kv-split partial blocks (frozen R8-R13) ----------------
struct PairBuf {
  bf16x8 k[2][2];   // [strip][k-span]
  bf16x8 v[4];      // [d-tile]
};

__global__ __launch_bounds__(256, 3) void attn_kernel(
    const __hip_bfloat16* __restrict__ Qg,
    const __hip_bfloat16* __restrict__ KSg,
    const __hip_bfloat16* __restrict__ VSg,
    float* __restrict__ OPg,       // [2][B_][SEQ][DH]
    float* __restrict__ PSg)       // [2][B_][SEQ]
{
  __shared__ float Osh[4][16][68];
  __shared__ float psums[4][64];

  const int tid  = threadIdx.x;
  const int wave = tid >> 6;
  const int lane = tid & 63;
  const int lrow = lane & 15;
  const int quad = lane >> 4;

  const int xcd   = blockIdx.x & 7;
  const int idx   = blockIdx.x >> 3;       // [0,128)
  const int b     = xcd >> 1;
  const int half  = idx & 1;
  const int qtile = (xcd & 1) * 64 + (idx >> 1);
  const int qbase = qtile * 64;

  const __hip_bfloat16* Qb  = Qg + ((size_t)b * SEQ + qbase) * DH;
  const __hip_bfloat16* kp0 = KSg + (size_t)b * KVSW_BATCH + half * 262144
                              + (size_t)wave * 65536 + lane * 8;
  const __hip_bfloat16* vp0 = VSg + (size_t)b * KVSW_BATCH + half * 262144
                              + (size_t)wave * 65536 + lane * 8;

  bf16x8 qf[4][2];
  #pragma unroll
  for (int mt = 0; mt < 4; ++mt)
    #pragma unroll
    for (int s = 0; s < 2; ++s)
      qf[mt][s] = *(const bf16x8*)(Qb + (mt * 16 + lrow) * DH + s * 32 + quad * 8);

  floatx4 oacc[4][4];   // [mt][dnt] — 64 acc regs (unified budget)
  #pragma unroll
  for (int mt = 0; mt < 4; ++mt)
    #pragma unroll
    for (int dnt = 0; dnt < 4; ++dnt)
      oacc[mt][dnt] = (floatx4){0.f, 0.f, 0.f, 0.f};
  float psum[4] = {0.f, 0.f, 0.f, 0.f};

  #pragma unroll 2
  for (int pair = 0; pair < 32; ++pair) {
    PairBuf pb;
    const __hip_bfloat16* kp = kp0 + pair * 2048;
    pb.k[0][0] = *(const bf16x8*)(kp);
    pb.k[0][1] = *(const bf16x8*)(kp + 512);
    pb.k[1][0] = *(const bf16x8*)(kp + 1024);
    pb.k[1][1] = *(const bf16x8*)(kp + 1536);
    const __hip_bfloat16* vp = vp0 + pair * 2048;
    #pragma unroll
    for (int dnt = 0; dnt < 4; ++dnt)
      pb.v[dnt] = *(const bf16x8*)(vp + dnt * 512);

    #pragma unroll
    for (int mt = 0; mt < 4; ++mt) {
      floatx4 s0 = (floatx4){0.f, 0.f, 0.f, 0.f};
      floatx4 s1 = (floatx4){0.f, 0.f, 0.f, 0.f};
      s0 = __builtin_amdgcn_mfma_f32_16x16x32_bf16(pb.k[0][0], qf[mt][0], s0, 0, 0, 0);
      s0 = __builtin_amdgcn_mfma_f32_16x16x32_bf16(pb.k[0][1], qf[mt][1], s0, 0, 0, 0);
      s1 = __builtin_amdgcn_mfma_f32_16x16x32_bf16(pb.k[1][0], qf[mt][0], s1, 0, 0, 0);
      s1 = __builtin_amdgcn_mfma_f32_16x16x32_bf16(pb.k[1][1], qf[mt][1], s1, 0, 0, 0);
      float p[8];
      #pragma unroll
      for (int r = 0; r < 4; ++r) {
        p[r]     = __builtin_amdgcn_exp2f(s0[r]);
        p[4 + r] = __builtin_amdgcn_exp2f(s1[r]);
      }
      psum[mt] += ((p[0] + p[1]) + (p[2] + p[3])) + ((p[4] + p[5]) + (p[6] + p[7]));
      bf16x8 pa;
      #pragma unroll
      for (int j = 0; j < 8; ++j) pa[j] = (__bf16)p[j];
      #pragma unroll
      for (int dnt = 0; dnt < 4; ++dnt)
        oacc[mt][dnt] = __builtin_amdgcn_mfma_f32_16x16x32_bf16(pa, pb.v[dnt], oacc[mt][dnt], 0, 0, 0);
    }
  }

  #pragma unroll
  for (int mt = 0; mt < 4; ++mt) {
    float s = psum[mt];
    s += __shfl_xor(s, 16, 64);
    s += __shfl_xor(s, 32, 64);
    psum[mt] = s;
  }
  if (quad == 0) {
    #pragma unroll
    for (int mt = 0; mt < 4; ++mt)
      psums[wave][mt * 16 + lrow] = psum[mt];
  }

  const size_t opbase = ((size_t)half * B_ + b) * SEQ + qbase;

  #pragma unroll
  for (int mt = 0; mt < 4; ++mt) {
    #pragma unroll
    for (int dnt = 0; dnt < 4; ++dnt)
      #pragma unroll
      for (int r = 0; r < 4; ++r)
        Osh[wave][quad * 4 + r][dnt * 16 + lrow] = oacc[mt][dnt][r];
    __syncthreads();

    {
      const int q16 = tid >> 4;
      const int d0  = (tid & 15) * 4;
      float4 a0 = *(const float4*)(&Osh[0][q16][d0]);
      float4 a1 = *(const float4*)(&Osh[1][q16][d0]);
      float4 a2 = *(const float4*)(&Osh[2][q16][d0]);
      float4 a3 = *(const float4*)(&Osh[3][q16][d0]);
      float4 res;
      res.x = (a0.x + a1.x) + (a2.x + a3.x);
      res.y = (a0.y + a1.y) + (a2.y + a3.y);
      res.z = (a0.z + a1.z) + (a2.z + a3.z);
      res.w = (a0.w + a1.w) + (a2.w + a3.w);
      *(float4*)(OPg + (opbase + mt * 16 + q16) * DH + d0) = res;
    }
    if (mt == 0 && tid < 64) {
      const float tot = (psums[0][tid] + psums[1][tid]) + (psums[2][tid] + psums[3][tid]);
      PSg[opbase + tid] = tot;
    }
    __syncthreads();
  }
}

// ---------------- kernel 3: out = merge(Opart)/denom @ wo + bo (frozen R13) ----------------
// grid 256 (1 block/CU), 512 threads. 16 rows x 256 cols. wo staged through
// LDS in K-tiles of 16 (reg-prefetch double buffer, one barrier per tile).
__global__ __launch_bounds__(512) void out_kernel(
    const float* __restrict__ OPg, const float* __restrict__ PSg,
    const float* __restrict__ wo, const float* __restrict__ bo,
    float* __restrict__ out)
{
  const int tid = threadIdx.x;
  const int b   = blockIdx.x >> 6;
  const int n0  = (blockIdx.x & 63) << 4;

  __shared__ __align__(16) float os[16][520];
  __shared__ __align__(16) float wot[2][16][260];
  __shared__ float invs[16][8];

  if (tid < 128) {
    const int r = tid >> 3, h = tid & 7;
    const size_t row = (size_t)b * SEQ + h * NSEQ + n0 + r;
    invs[r][h] = 1.0f / (PSg[row] + PSg[(size_t)B_ * SEQ + row]);
  }
  __syncthreads();

  // gather + merge halves + normalize -> os
  for (int i = tid; i < 2048; i += 512) {
    const int r  = i >> 7;
    const int c4 = (i & 127) * 4;
    const int h  = c4 >> 6;
    const size_t idx = ((size_t)b * SEQ + h * NSEQ + n0 + r) * DH + (c4 & 63);
    const float4 p0 = *(const float4*)(OPg + idx);
    const float4 p1 = *(const float4*)(OPg + (size_t)B_ * SEQ * DH + idx);
    const float inv = invs[r][c4 >> 6];
    float4 m;
    m.x = (p0.x + p1.x) * inv;
    m.y = (p0.y + p1.y) * inv;
    m.z = (p0.z + p1.z) * inv;
    m.w = (p0.w + p1.w) * inv;
    *(float4*)(&os[r][c4]) = m;
  }

  // stage tile 0 of wo (chunks: krow = c>>6, col = (c&63)*4)
  {
    const int c0 = tid, c1 = tid + 512;
    const float4 v0 = *(const float4*)(wo + (size_t)(c0 >> 6) * QS + (c0 & 63) * 4);
    const float4 v1 = *(const float4*)(wo + (size_t)(c1 >> 6) * QS + (c1 & 63) * 4);
    *(float4*)(&wot[0][c0 >> 6][(c0 & 63) * 4]) = v0;
    *(float4*)(&wot[0][c1 >> 6][(c1 & 63) * 4]) = v1;
  }
  __syncthreads();

  const int oq = tid & 63;      // col group: o = oq*4
  const int rq = tid >> 6;      // row pair: rows rq*2, rq*2+1
  const int o  = oq * 4;
  const int r0 = rq * 2;

  float acc[2][4];
  #pragma unroll
  for (int i = 0; i < 2; ++i)
    #pragma unroll
    for (int j = 0; j < 4; ++j) acc[i][j] = 0.f;

  for (int kt = 0; kt < 32; ++kt) {
    const int cur = kt & 1;
    // prefetch next tile into registers (latency hidden by compute below)
    float4 pf0, pf1;
    const int c0 = tid, c1 = tid + 512;
    if (kt < 31) {
      const int kb = (kt + 1) * 16;
      pf0 = *(const float4*)(wo + (size_t)(kb + (c0 >> 6)) * QS + (c0 & 63) * 4);
      pf1 = *(const float4*)(wo + (size_t)(kb + (c1 >> 6)) * QS + (c1 & 63) * 4);
    }

    // compute this tile
    const int kbase = kt * 16;
    #pragma unroll
    for (int kq = 0; kq < 4; ++kq) {
      const float4 ov0 = *(const float4*)(&os[r0][kbase + kq * 4]);       // broadcast
      const float4 ov1 = *(const float4*)(&os[r0 + 1][kbase + kq * 4]);   // broadcast
      #pragma unroll
      for (int j = 0; j < 4; ++j) {
        const float4 w = *(const float4*)(&wot[cur][kq * 4 + j][o]);
        const float a = (j == 0) ? ov0.x : (j == 1) ? ov0.y : (j == 2) ? ov0.z : ov0.w;
        const float bq = (j == 0) ? ov1.x : (j == 1) ? ov1.y : (j == 2) ? ov1.z : ov1.w;
        acc[0][0] += a * w.x; acc[0][1] += a * w.y;
        acc[0][2] += a * w.z; acc[0][3] += a * w.w;
        acc[1][0] += bq * w.x; acc[1][1] += bq * w.y;
        acc[1][2] += bq * w.z; acc[1][3] += bq * w.w;
      }
    }

    if (kt < 31) {
      *(float4*)(&wot[cur ^ 1][c0 >> 6][(c0 & 63) * 4]) = pf0;
      *(float4*)(&wot[cur ^ 1][c1 >> 6][(c1 & 63) * 4]) = pf1;
    }
    __syncthreads();
  }

  const float4 bv = *(const float4*)(bo + o);
  #pragma unroll
  for (int ri = 0; ri < 2; ++ri) {
    float4 res;
    res.x = acc[ri][0] + bv.x;
    res.y = acc[ri][1] + bv.y;
    res.z = acc[ri][2] + bv.z;
    res.w = acc[ri][3] + bv.w;
    *(float4*)(out + ((size_t)b * NSEQ + n0 + r0 + ri) * QS + o) = res;
  }
}

extern "C" void kernel_launch(void* const* d_in, const int* in_sizes, int n_in,
                              void* d_out, int out_size, void* d_ws, size_t ws_size,
                              hipStream_t stream) {
  const float* x   = (const float*)d_in[0];
  const float* wq1 = (const float*)d_in[1];
  const float* wq2 = (const float*)d_in[2];
  const float* wk1 = (const float*)d_in[3];
  const float* wk2 = (const float*)d_in[4];
  const float* wv1 = (const float*)d_in[5];
  const float* wv2 = (const float*)d_in[6];
  const float* wo  = (const float*)d_in[7];
  const float* bo  = (const float*)d_in[8];
  float* out = (float*)d_out;

  __hip_bfloat16* Qg  = (__hip_bfloat16*)d_ws;
  __hip_bfloat16* KSg = Qg + (size_t)B_ * SEQ * DH;
  __hip_bfloat16* VSg = KSg + (size_t)B_ * KVSW_BATCH;
  float*          OPg = (float*)(VSg + (size_t)B_ * KVSW_BATCH);   // [2][B_][SEQ][DH]
  float*          PSg = OPg + 2 * (size_t)B_ * SEQ * DH;           // [2][B_][SEQ]

  qkv_kernel<<<768, 512, 0, stream>>>(x, wq1, wq2, wk1, wk2, wv1, wv2, Qg, KSg, VSg);
  attn_kernel<<<1024, 256, 0, stream>>>(Qg, KSg, VSg, OPg, PSg);
  out_kernel<<<256, 512, 0, stream>>>(OPg, PSg, wo, bo, out);
}

// Round 3
// 179.938 us; speedup vs baseline: 2.6007x; 1.0666x over previous
//
#include <hip/hip_runtime.h>
#include <hip/hip_bf16.h>

// CrossAttention: b=4, n=1024, qs=256, heads=8, dim_head=64, bottleneck=40.
// Attention = full 8192x8192 softmax-attention per batch over D=64.
//
// R16:
//  - attn: frozen (72.7us, MfmaUtil 40%).
//  - qkv: frozen R15 body; grid 768->776 — 8 appended blocks convert wo to
//    fragment-ordered bf16 hi/lo (wob) for the out MFMA GEMM.
//  - out: REWRITTEN as MFMA GEMM. fp32-VALU version had a ~30us LDS-instr
//    floor (8 waves x 24 ds_read x 12cyc x 32kt, CU-serialized). MFMA's
//    A-broadcast needs ~2 LDS/L2 reads per 16x16x32 tile. bf16x2 hi/lo
//    split (D = AhBh + AhBl + AlBh) keeps fp32-level accuracy.
//
// Workspace: Q 4MB | K_sw 4MB | V_sw 4MB | Opart 2x8MB | psum 2x128KB
//            | wob hi/lo 2x256KB ~ 28.8MB.

#define B_    4
#define H_    8
#define NSEQ  1024
#define SEQ   8192        // H_*NSEQ
#define DH    64
#define QS    256
#define INNER 512
#define QSCALE 0.18033688011112042f   // (1/sqrt(64)) * log2(e)

#define KVSW_BATCH 524288             // elems per batch in K_sw / V_sw
#define OPHALF (2097152)              // B_*SEQ*DH

typedef __bf16 bf16x8 __attribute__((ext_vector_type(8)));
typedef float floatx4 __attribute__((ext_vector_type(4)));

// ---------------- kernel 1: QKV projections + fragment-order swizzle ----------------
// grid 776: [0,768) = p*256 + b*64 + nblk (one projection per block, 512 thr,
// 16 x-rows); [768,776) = wo -> wob bf16 hi/lo fragment conversion.
__global__ __launch_bounds__(512, 4) void qkv_kernel(
    const float* __restrict__ x,
    const float* __restrict__ wq1, const float* __restrict__ wq2,
    const float* __restrict__ wk1, const float* __restrict__ wk2,
    const float* __restrict__ wv1, const float* __restrict__ wv2,
    const float* __restrict__ wo,
    __hip_bfloat16* __restrict__ Qg, __hip_bfloat16* __restrict__ KSg,
    __hip_bfloat16* __restrict__ VSg,
    __hip_bfloat16* __restrict__ WOBH, __hip_bfloat16* __restrict__ WOBL)
{
  const int tid  = threadIdx.x;

  if (blockIdx.x >= 768) {
    // ---- wo conversion: task T in [0,16384): n = T&255, k8 = T>>8.
    // frag elem: nt=n>>4, kc=k8>>2, lane=(n&15)+16*(k8&3), j=k&7.
    const int cid = blockIdx.x - 768;
    const int t4  = (cid * 512 + tid) * 4;
    const int n   = t4 & 255;
    const int k8  = t4 >> 8;
    float4 rr[8];
    #pragma unroll
    for (int kk = 0; kk < 8; ++kk)
      rr[kk] = *(const float4*)(wo + (size_t)(k8 * 8 + kk) * QS + n);
    const int kc = k8 >> 2, qq = k8 & 3;
    #pragma unroll
    for (int nn = 0; nn < 4; ++nn) {
      const int nc = n + nn;
      const int l  = (nc & 15) + 16 * qq;
      const size_t off = ((size_t)((nc >> 4) * 16 + kc) * 64 + l) * 8;
      bf16x8 hv, lv;
      #pragma unroll
      for (int kk = 0; kk < 8; ++kk) {
        const float v = (nn == 0) ? rr[kk].x : (nn == 1) ? rr[kk].y
                      : (nn == 2) ? rr[kk].z : rr[kk].w;
        const __bf16 h16 = (__bf16)v;
        hv[kk] = h16;
        lv[kk] = (__bf16)(v - (float)h16);
      }
      *(bf16x8*)(WOBH + off) = hv;
      *(bf16x8*)(WOBL + off) = lv;
    }
    return;
  }

  const int p    = blockIdx.x >> 8;        // 0=Q 1=K 2=V
  const int rest = blockIdx.x & 255;
  const int b    = rest >> 6;
  const int nblk = rest & 63;
  const int n0   = nblk << 4;

  __shared__ __align__(16) float xs[16][260];
  __shared__ __align__(16) float tb2[4][16][40];   // k-split partials
  __shared__ __align__(16) float tb[16][40];
  // union buffer: q/k view [16][520] bf16 (8320), v view [512][20] (10240)
  __shared__ __align__(16) __hip_bfloat16 ob[10400];

  const float* w1 = (p == 0) ? wq1 : (p == 1) ? wk1 : wv1;
  const float* w2 = (p == 0) ? wq2 : (p == 1) ? wk2 : wv2;

  // stage x tile: 1024 float4 tasks, 2 per thread
  #pragma unroll
  for (int j = 0; j < 2; ++j) {
    const int i  = tid + j * 512;
    const int r  = i >> 6;
    const int c4 = (i & 63) << 2;
    *(float4*)(&xs[r][c4]) =
        *(const float4*)(x + ((size_t)b * NSEQ + n0 + r) * QS + c4);
  }
  __syncthreads();

  // stage 1a: bottleneck partials, k-split x4. 640 tasks (1-2 per thread).
  for (int t = tid; t < 640; t += 512) {
    const int ks  = t / 160;
    const int rem = t - ks * 160;
    const int r   = rem / 10;
    const int bn  = (rem - r * 10) * 4;
    float a0 = 0.f, a1 = 0.f, a2 = 0.f, a3 = 0.f;
    #pragma unroll 4
    for (int c4 = ks * 16; c4 < ks * 16 + 16; ++c4) {
      const float4 xv = *(const float4*)(&xs[r][c4 * 4]);
      const float4 wa = *(const float4*)(w1 + (c4 * 4 + 0) * 40 + bn);
      const float4 wb = *(const float4*)(w1 + (c4 * 4 + 1) * 40 + bn);
      const float4 wc = *(const float4*)(w1 + (c4 * 4 + 2) * 40 + bn);
      const float4 wd = *(const float4*)(w1 + (c4 * 4 + 3) * 40 + bn);
      a0 += xv.x * wa.x + xv.y * wb.x + xv.z * wc.x + xv.w * wd.x;
      a1 += xv.x * wa.y + xv.y * wb.y + xv.z * wc.y + xv.w * wd.y;
      a2 += xv.x * wa.z + xv.y * wb.z + xv.z * wc.z + xv.w * wd.z;
      a3 += xv.x * wa.w + xv.y * wb.w + xv.z * wc.w + xv.w * wd.w;
    }
    tb2[ks][r][bn + 0] = a0; tb2[ks][r][bn + 1] = a1;
    tb2[ks][r][bn + 2] = a2; tb2[ks][r][bn + 3] = a3;
  }
  __syncthreads();

  // stage 1b: combine quarters + SiLU on K path.
  if (tid < 160) {
    const int r  = tid / 10;
    const int bn = (tid - r * 10) * 4;
    const float4 h0 = *(const float4*)(&tb2[0][r][bn]);
    const float4 h1 = *(const float4*)(&tb2[1][r][bn]);
    const float4 h2 = *(const float4*)(&tb2[2][r][bn]);
    const float4 h3 = *(const float4*)(&tb2[3][r][bn]);
    float a0 = (h0.x + h1.x) + (h2.x + h3.x);
    float a1 = (h0.y + h1.y) + (h2.y + h3.y);
    float a2 = (h0.z + h1.z) + (h2.z + h3.z);
    float a3 = (h0.w + h1.w) + (h2.w + h3.w);
    if (p == 1) {
      a0 = a0 / (1.f + __expf(-a0));
      a1 = a1 / (1.f + __expf(-a1));
      a2 = a2 / (1.f + __expf(-a2));
      a3 = a3 / (1.f + __expf(-a3));
    }
    tb[r][bn + 0] = a0; tb[r][bn + 1] = a1;
    tb[r][bn + 2] = a2; tb[r][bn + 3] = a3;
  }
  __syncthreads();

  // stage 2: 40 -> 512, single pass. thread = 4 rows x 4 cols.
  {
    const int cq = tid & 127;
    const int rq = tid >> 7;            // [0,4)
    const int c  = cq * 4, r0 = rq * 4;
    const float scale = (p == 0) ? QSCALE : 1.0f;
    float acc[4][4];
    #pragma unroll
    for (int i = 0; i < 4; ++i)
      #pragma unroll
      for (int j = 0; j < 4; ++j) acc[i][j] = 0.f;

    #pragma unroll 2
    for (int jb = 0; jb < 10; ++jb) {
      const float4 w0  = *(const float4*)(w2 + (jb * 4 + 0) * INNER + c);
      const float4 w1r = *(const float4*)(w2 + (jb * 4 + 1) * INNER + c);
      const float4 w2r = *(const float4*)(w2 + (jb * 4 + 2) * INNER + c);
      const float4 w3  = *(const float4*)(w2 + (jb * 4 + 3) * INNER + c);
      #pragma unroll
      for (int ri = 0; ri < 4; ++ri) {
        const float4 tv = *(const float4*)(&tb[r0 + ri][jb * 4]);   // wave-broadcast
        acc[ri][0] += tv.x * w0.x + tv.y * w1r.x + tv.z * w2r.x + tv.w * w3.x;
        acc[ri][1] += tv.x * w0.y + tv.y * w1r.y + tv.z * w2r.y + tv.w * w3.y;
        acc[ri][2] += tv.x * w0.z + tv.y * w1r.z + tv.z * w2r.z + tv.w * w3.z;
        acc[ri][3] += tv.x * w0.w + tv.y * w1r.w + tv.z * w2r.w + tv.w * w3.w;
      }
    }
    #pragma unroll
    for (int ri = 0; ri < 4; ++ri)
      #pragma unroll
      for (int ci = 0; ci < 4; ++ci) {
        const int cc = c + ci;
        const float v = acc[ri][ci] * scale;
        if (p == 2) ob[cc * 20 + r0 + ri]    = __float2bfloat16(v);   // vb[cc][r]
        else        ob[(r0 + ri) * 520 + cc] = __float2bfloat16(v);   // qb/kb[r][cc]
      }
  }
  __syncthreads();

  if (p == 0) {
    // ---- Q write: 1024 float4 tasks, 2 per thread ----
    #pragma unroll
    for (int j = 0; j < 2; ++j) {
      const int i  = tid + j * 512;
      const int h  = i >> 7;
      const int r  = (i >> 3) & 15;
      const int d8 = i & 7;
      *(float4*)(Qg + ((size_t)b * SEQ + h * NSEQ + n0 + r) * DH + d8 * 8) =
          *(const float4*)(&ob[r * 520 + h * 64 + d8 * 8]);
    }
  } else if (p == 1) {
    // ---- K_sw write: 1024 float4 tasks (t16 = h*64+nblk), 2 per thread ----
    #pragma unroll
    for (int j = 0; j < 2; ++j) {
      const int i    = tid + j * 512;
      const int h    = i >> 7;
      const int ks2  = (i >> 6) & 1;
      const int quad = (i >> 4) & 3;
      const int r    = i & 15;
      const int lane = quad * 16 + r;
      const size_t dst = (size_t)b * KVSW_BATCH
          + ((size_t)((h * 64 + nblk) * 2 + ks2) * 64 + lane) * 8;
      *(float4*)(KSg + dst) = *(const float4*)(&ob[r * 520 + h * 64 + ks2 * 32 + quad * 8]);
    }
  } else {
    // ---- V_sw write: 2048 uint2 tasks, 4 per thread ----
    const int st  = nblk & 1;
    const int p32 = nblk >> 1;
    #pragma unroll
    for (int pass = 0; pass < 4; ++pass) {
      const int i   = tid + pass * 512;
      const int h   = i >> 8;
      const int dnt = (i >> 6) & 3;
      const int dm  = (i >> 2) & 15;
      const int rg  = i & 3;
      const int lane = rg * 16 + dm;
      const size_t dst = (size_t)b * KVSW_BATCH
          + ((size_t)((h * 32 + p32) * 4 + dnt) * 64 + lane) * 8 + st * 4;
      *(uint2*)(VSg + dst) = *(const uint2*)(&ob[(h * 64 + dnt * 16 + dm) * 20 + rg * 4]);
    }
  }
}

// ---------------- kernel 2: attention, kv-split partial blocks (frozen R8-R13) ----------------
struct PairBuf {
  bf16x8 k[2][2];   // [strip][k-span]
  bf16x8 v[4];      // [d-tile]
};

__global__ __launch_bounds__(256, 3) void attn_kernel(
    const __hip_bfloat16* __restrict__ Qg,
    const __hip_bfloat16* __restrict__ KSg,
    const __hip_bfloat16* __restrict__ VSg,
    float* __restrict__ OPg,       // [2][B_][SEQ][DH]
    float* __restrict__ PSg)       // [2][B_][SEQ]
{
  __shared__ float Osh[4][16][68];
  __shared__ float psums[4][64];

  const int tid  = threadIdx.x;
  const int wave = tid >> 6;
  const int lane = tid & 63;
  const int lrow = lane & 15;
  const int quad = lane >> 4;

  const int xcd   = blockIdx.x & 7;
  const int idx   = blockIdx.x >> 3;       // [0,128)
  const int b     = xcd >> 1;
  const int half  = idx & 1;
  const int qtile = (xcd & 1) * 64 + (idx >> 1);
  const int qbase = qtile * 64;

  const __hip_bfloat16* Qb  = Qg + ((size_t)b * SEQ + qbase) * DH;
  const __hip_bfloat16* kp0 = KSg + (size_t)b * KVSW_BATCH + half * 262144
                              + (size_t)wave * 65536 + lane * 8;
  const __hip_bfloat16* vp0 = VSg + (size_t)b * KVSW_BATCH + half * 262144
                              + (size_t)wave * 65536 + lane * 8;

  bf16x8 qf[4][2];
  #pragma unroll
  for (int mt = 0; mt < 4; ++mt)
    #pragma unroll
    for (int s = 0; s < 2; ++s)
      qf[mt][s] = *(const bf16x8*)(Qb + (mt * 16 + lrow) * DH + s * 32 + quad * 8);

  floatx4 oacc[4][4];   // [mt][dnt] — 64 acc regs (unified budget)
  #pragma unroll
  for (int mt = 0; mt < 4; ++mt)
    #pragma unroll
    for (int dnt = 0; dnt < 4; ++dnt)
      oacc[mt][dnt] = (floatx4){0.f, 0.f, 0.f, 0.f};
  float psum[4] = {0.f, 0.f, 0.f, 0.f};

  #pragma unroll 2
  for (int pair = 0; pair < 32; ++pair) {
    PairBuf pb;
    const __hip_bfloat16* kp = kp0 + pair * 2048;
    pb.k[0][0] = *(const bf16x8*)(kp);
    pb.k[0][1] = *(const bf16x8*)(kp + 512);
    pb.k[1][0] = *(const bf16x8*)(kp + 1024);
    pb.k[1][1] = *(const bf16x8*)(kp + 1536);
    const __hip_bfloat16* vp = vp0 + pair * 2048;
    #pragma unroll
    for (int dnt = 0; dnt < 4; ++dnt)
      pb.v[dnt] = *(const bf16x8*)(vp + dnt * 512);

    #pragma unroll
    for (int mt = 0; mt < 4; ++mt) {
      floatx4 s0 = (floatx4){0.f, 0.f, 0.f, 0.f};
      floatx4 s1 = (floatx4){0.f, 0.f, 0.f, 0.f};
      s0 = __builtin_amdgcn_mfma_f32_16x16x32_bf16(pb.k[0][0], qf[mt][0], s0, 0, 0, 0);
      s0 = __builtin_amdgcn_mfma_f32_16x16x32_bf16(pb.k[0][1], qf[mt][1], s0, 0, 0, 0);
      s1 = __builtin_amdgcn_mfma_f32_16x16x32_bf16(pb.k[1][0], qf[mt][0], s1, 0, 0, 0);
      s1 = __builtin_amdgcn_mfma_f32_16x16x32_bf16(pb.k[1][1], qf[mt][1], s1, 0, 0, 0);
      float p[8];
      #pragma unroll
      for (int r = 0; r < 4; ++r) {
        p[r]     = __builtin_amdgcn_exp2f(s0[r]);
        p[4 + r] = __builtin_amdgcn_exp2f(s1[r]);
      }
      psum[mt] += ((p[0] + p[1]) + (p[2] + p[3])) + ((p[4] + p[5]) + (p[6] + p[7]));
      bf16x8 pa;
      #pragma unroll
      for (int j = 0; j < 8; ++j) pa[j] = (__bf16)p[j];
      #pragma unroll
      for (int dnt = 0; dnt < 4; ++dnt)
        oacc[mt][dnt] = __builtin_amdgcn_mfma_f32_16x16x32_bf16(pa, pb.v[dnt], oacc[mt][dnt], 0, 0, 0);
    }
  }

  #pragma unroll
  for (int mt = 0; mt < 4; ++mt) {
    float s = psum[mt];
    s += __shfl_xor(s, 16, 64);
    s += __shfl_xor(s, 32, 64);
    psum[mt] = s;
  }
  if (quad == 0) {
    #pragma unroll
    for (int mt = 0; mt < 4; ++mt)
      psums[wave][mt * 16 + lrow] = psum[mt];
  }

  const size_t opbase = ((size_t)half * B_ + b) * SEQ + qbase;

  #pragma unroll
  for (int mt = 0; mt < 4; ++mt) {
    #pragma unroll
    for (int dnt = 0; dnt < 4; ++dnt)
      #pragma unroll
      for (int r = 0; r < 4; ++r)
        Osh[wave][quad * 4 + r][dnt * 16 + lrow] = oacc[mt][dnt][r];
    __syncthreads();

    {
      const int q16 = tid >> 4;
      const int d0  = (tid & 15) * 4;
      float4 a0 = *(const float4*)(&Osh[0][q16][d0]);
      float4 a1 = *(const float4*)(&Osh[1][q16][d0]);
      float4 a2 = *(const float4*)(&Osh[2][q16][d0]);
      float4 a3 = *(const float4*)(&Osh[3][q16][d0]);
      float4 res;
      res.x = (a0.x + a1.x) + (a2.x + a3.x);
      res.y = (a0.y + a1.y) + (a2.y + a3.y);
      res.z = (a0.z + a1.z) + (a2.z + a3.z);
      res.w = (a0.w + a1.w) + (a2.w + a3.w);
      *(float4*)(OPg + (opbase + mt * 16 + q16) * DH + d0) = res;
    }
    if (mt == 0 && tid < 64) {
      const float tot = (psums[0][tid] + psums[1][tid]) + (psums[2][tid] + psums[3][tid]);
      PSg[opbase + tid] = tot;
    }
    __syncthreads();
  }
}

// ---------------- kernel 3: out = merge(Opart)/denom @ wo + bo — MFMA ----------------
// grid 256 (b*64 + nblk), 256 threads (4 waves). Per block: 16 rows x 256 cols.
// Phase 1: merge+normalize OPg halves -> bf16 hi/lo A-fragments in LDS
// (packed [kc][lane][8], contiguous per-wave ds ops).
// Phase 2: each wave owns 4 N-tiles; B-frags (wob hi/lo) streamed from L2;
// D = AhBh + AhBl + AlBh in 3 independent MFMA chains (fp32-level accuracy).
__global__ __launch_bounds__(256, 1) void out_kernel(
    const float* __restrict__ OPg, const float* __restrict__ PSg,
    const __hip_bfloat16* __restrict__ WOBH, const __hip_bfloat16* __restrict__ WOBL,
    const float* __restrict__ bo, float* __restrict__ out)
{
  __shared__ __align__(16) __hip_bfloat16 apH[8192];   // [kc][lane][8]
  __shared__ __align__(16) __hip_bfloat16 apL[8192];
  __shared__ float invs[16][8];

  const int tid  = threadIdx.x;
  const int b    = blockIdx.x >> 6;
  const int n0   = (blockIdx.x & 63) << 4;
  const int lane = tid & 63;
  const int wave = tid >> 6;

  if (tid < 128) {
    const int r = tid >> 3, h = tid & 7;
    const size_t row = (size_t)b * SEQ + h * NSEQ + n0 + r;
    invs[r][h] = 1.0f / (PSg[row] + PSg[(size_t)B_ * SEQ + row]);
  }
  __syncthreads();

  // ---- phase 1: merge halves + normalize -> hi/lo A-frag pack.
  // task i: m=i&15, q=(i>>4)&3, kc=i>>6; k8 = q + 4*kc (8 consecutive k).
  {
    const int m   = tid & 15;
    const int q   = (tid >> 4) & 3;
    const int kc0 = tid >> 6;
    #pragma unroll
    for (int pss = 0; pss < 4; ++pss) {
      const int kc = kc0 + pss * 4;
      const int h  = kc >> 1;
      const int dh = (q + 4 * (kc & 1)) * 8;
      const size_t idx = (((size_t)b * H_ + h) * NSEQ + n0 + m) * DH + dh;
      const float4 a0 = *(const float4*)(OPg + idx);
      const float4 a1 = *(const float4*)(OPg + idx + 4);
      const float4 b0 = *(const float4*)(OPg + OPHALF + idx);
      const float4 b1 = *(const float4*)(OPg + OPHALF + idx + 4);
      const float inv = invs[m][h];
      float v[8];
      v[0] = (a0.x + b0.x) * inv; v[1] = (a0.y + b0.y) * inv;
      v[2] = (a0.z + b0.z) * inv; v[3] = (a0.w + b0.w) * inv;
      v[4] = (a1.x + b1.x) * inv; v[5] = (a1.y + b1.y) * inv;
      v[6] = (a1.z + b1.z) * inv; v[7] = (a1.w + b1.w) * inv;
      bf16x8 hv, lv;
      #pragma unroll
      for (int j = 0; j < 8; ++j) {
        const __bf16 h16 = (__bf16)v[j];
        hv[j] = h16;
        lv[j] = (__bf16)(v[j] - (float)h16);
      }
      const int off = (kc * 64 + (m + 16 * q)) * 8;
      *(bf16x8*)(apH + off) = hv;
      *(bf16x8*)(apL + off) = lv;
    }
  }
  __syncthreads();

  // ---- phase 2: MFMA. A-frags (all 16 kc, hi+lo) -> 128 VGPR, B from L2.
  bf16x8 ah[16], al[16];
  #pragma unroll
  for (int kc = 0; kc < 16; ++kc) {
    ah[kc] = *(const bf16x8*)(apH + (kc * 64 + lane) * 8);
    al[kc] = *(const bf16x8*)(apL + (kc * 64 + lane) * 8);
  }

  const int colq = lane & 15;
  const int quad = lane >> 4;

  #pragma unroll
  for (int nt4 = 0; nt4 < 4; ++nt4) {
    const int nt = nt4 * 4 + wave;
    const __hip_bfloat16* wbh = WOBH + ((size_t)nt * 16 * 64 + lane) * 8;
    const __hip_bfloat16* wbl = WOBL + ((size_t)nt * 16 * 64 + lane) * 8;
    floatx4 aHH = (floatx4){0.f, 0.f, 0.f, 0.f};
    floatx4 aHL = (floatx4){0.f, 0.f, 0.f, 0.f};
    floatx4 aLH = (floatx4){0.f, 0.f, 0.f, 0.f};
    #pragma unroll
    for (int kg = 0; kg < 4; ++kg) {
      bf16x8 bh[4], bl[4];
      #pragma unroll
      for (int j = 0; j < 4; ++j) {
        bh[j] = *(const bf16x8*)(wbh + (kg * 4 + j) * 512);
        bl[j] = *(const bf16x8*)(wbl + (kg * 4 + j) * 512);
      }
      #pragma unroll
      for (int j = 0; j < 4; ++j) {
        const int kc = kg * 4 + j;
        aHH = __builtin_amdgcn_mfma_f32_16x16x32_bf16(ah[kc], bh[j], aHH, 0, 0, 0);
        aHL = __builtin_amdgcn_mfma_f32_16x16x32_bf16(ah[kc], bl[j], aHL, 0, 0, 0);
        aLH = __builtin_amdgcn_mfma_f32_16x16x32_bf16(al[kc], bh[j], aLH, 0, 0, 0);
      }
    }
    const int n  = nt * 16 + colq;
    const float bv = bo[n];
    #pragma unroll
    for (int r = 0; r < 4; ++r) {
      const int mm = quad * 4 + r;
      out[((size_t)b * NSEQ + n0 + mm) * QS + n] =
          ((aHH[r] + aHL[r]) + aLH[r]) + bv;
    }
  }
}

extern "C" void kernel_launch(void* const* d_in, const int* in_sizes, int n_in,
                              void* d_out, int out_size, void* d_ws, size_t ws_size,
                              hipStream_t stream) {
  const float* x   = (const float*)d_in[0];
  const float* wq1 = (const float*)d_in[1];
  const float* wq2 = (const float*)d_in[2];
  const float* wk1 = (const float*)d_in[3];
  const float* wk2 = (const float*)d_in[4];
  const float* wv1 = (const float*)d_in[5];
  const float* wv2 = (const float*)d_in[6];
  const float* wo  = (const float*)d_in[7];
  const float* bo  = (const float*)d_in[8];
  float* out = (float*)d_out;

  __hip_bfloat16* Qg  = (__hip_bfloat16*)d_ws;
  __hip_bfloat16* KSg = Qg + (size_t)B_ * SEQ * DH;
  __hip_bfloat16* VSg = KSg + (size_t)B_ * KVSW_BATCH;
  float*          OPg = (float*)(VSg + (size_t)B_ * KVSW_BATCH);   // [2][B_][SEQ][DH]
  float*          PSg = OPg + 2 * (size_t)B_ * SEQ * DH;           // [2][B_][SEQ]
  __hip_bfloat16* WOBH = (__hip_bfloat16*)(PSg + 2 * (size_t)B_ * SEQ);
  __hip_bfloat16* WOBL = WOBH + (size_t)INNER * QS;

  qkv_kernel<<<776, 512, 0, stream>>>(x, wq1, wq2, wk1, wk2, wv1, wv2, wo,
                                      Qg, KSg, VSg, WOBH, WOBL);
  attn_kernel<<<1024, 256, 0, stream>>>(Qg, KSg, VSg, OPg, PSg);
  out_kernel<<<256, 256, 0, stream>>>(OPg, PSg, WOBH, WOBL, bo, out);
}

// Round 4
// 165.173 us; speedup vs baseline: 2.8331x; 1.0894x over previous
//
#include <hip/hip_runtime.h>
#include <hip/hip_bf16.h>

// CrossAttention: b=4, n=1024, qs=256, heads=8, dim_head=64, bottleneck=40.
// Attention = full 8192x8192 softmax-attention per batch over D=64.
//
// R17:
//  - NEW conv_kernel (80 blocks, launched first): converts w1cat/w2/wo to
//    bf16 hi/lo MFMA fragments (w1cat = [wq1|wk1|wv1|pad0] 256x128; w2
//    K-padded 40->64 per proj; wo as R16).
//  - qkv: REWRITTEN as MFMA GEMM (was ~60us, VMEM-issue-bound: 61k global
//    loads/block). grid 256 fused-proj blocks, 512 thr. Stage1: 24 MFMA/wave
//    hi/lo 3-chain; SiLU fp32 on cat cols [40,80); stage2: 72 MFMA/wave.
//    Reuses R16 out_kernel's HARNESS-VERIFIED fragment convention:
//      A: lane=m+16q, elem j -> k=kc*32+q*8+j; B: lane=n+16q;
//      D: col=lane&15, row=(lane>>4)*4+reg.
//    Q/K_sw/V_sw global write phases byte-identical to R15.
//  - attn: frozen (74us, MfmaUtil 40%). out: frozen (R16 MFMA version).
//
// Workspace: Q|K_sw|V_sw 12MB | Opart 16MB | psum 256KB | WOB 512KB |
//            W1B 128KB | W2B 384KB ~ 29.3MB.

#define B_    4
#define H_    8
#define NSEQ  1024
#define SEQ   8192        // H_*NSEQ
#define DH    64
#define QS    256
#define INNER 512
#define QSCALE 0.18033688011112042f   // (1/sqrt(64)) * log2(e)

#define KVSW_BATCH 524288             // elems per batch in K_sw / V_sw
#define OPHALF (2097152)              // B_*SEQ*DH

typedef __bf16 bf16x8 __attribute__((ext_vector_type(8)));
typedef float floatx4 __attribute__((ext_vector_type(4)));

// ---------------- kernel 0: weight -> bf16 hi/lo fragment conversion ----------------
// grid 80, 256 thr. blocks [0,16): w1cat (256x128, cols 120-127 zero);
// [16,64): w2 per proj (K 40->64 zero-pad, N=512); [64,80): wo (as R16).
__global__ __launch_bounds__(256) void conv_kernel(
    const float* __restrict__ wq1, const float* __restrict__ wk1,
    const float* __restrict__ wv1,
    const float* __restrict__ wq2, const float* __restrict__ wk2,
    const float* __restrict__ wv2,
    const float* __restrict__ wo,
    __hip_bfloat16* __restrict__ W1BH, __hip_bfloat16* __restrict__ W1BL,
    __hip_bfloat16* __restrict__ W2BH, __hip_bfloat16* __restrict__ W2BL,
    __hip_bfloat16* __restrict__ WOBH, __hip_bfloat16* __restrict__ WOBL)
{
  const int tid = threadIdx.x;
  const int blk = blockIdx.x;

  if (blk < 16) {
    // ---- W1B: task t -> n = t&127, kq = t>>7 (kc = kq>>2, q = kq&3)
    const int t  = blk * 256 + tid;
    const int n  = t & 127;
    const int kq = t >> 7;
    const int kc = kq >> 2, q = kq & 3;
    const float* src; int col;
    if (n < 40)       { src = wq1; col = n; }
    else if (n < 80)  { src = wk1; col = n - 40; }
    else if (n < 120) { src = wv1; col = n - 80; }
    else              { src = nullptr; col = 0; }
    bf16x8 hv, lv;
    #pragma unroll
    for (int j = 0; j < 8; ++j) {
      const int k = kc * 32 + q * 8 + j;
      const float v = src ? src[k * 40 + col] : 0.f;
      const __bf16 h16 = (__bf16)v;
      hv[j] = h16; lv[j] = (__bf16)(v - (float)h16);
    }
    const size_t off = (((size_t)(n >> 4) * 8 + kc) * 64 + (n & 15) + 16 * q) * 8;
    *(bf16x8*)(W1BH + off) = hv;
    *(bf16x8*)(W1BL + off) = lv;
  } else if (blk < 64) {
    // ---- W2B: task t -> n = t&511, r = t>>9 (p = r>>3, kc = (r>>2)&1, q = r&3)
    const int t  = (blk - 16) * 256 + tid;
    const int n  = t & 511;
    const int r  = t >> 9;                    // [0,24)
    const int p  = r >> 3;
    const int kq = r & 7;
    const int kc = kq >> 2, q = kq & 3;
    const float* w2 = (p == 0) ? wq2 : (p == 1) ? wk2 : wv2;
    bf16x8 hv, lv;
    #pragma unroll
    for (int j = 0; j < 8; ++j) {
      const int k = kc * 32 + q * 8 + j;
      const float v = (k < 40) ? w2[(size_t)k * 512 + n] : 0.f;
      const __bf16 h16 = (__bf16)v;
      hv[j] = h16; lv[j] = (__bf16)(v - (float)h16);
    }
    const size_t off = ((((size_t)p * 32 + (n >> 4)) * 2 + kc) * 64 + (n & 15) + 16 * q) * 8;
    *(bf16x8*)(W2BH + off) = hv;
    *(bf16x8*)(W2BL + off) = lv;
  } else {
    // ---- WOB: identical math to R16 (harness-verified), re-strided to 256 thr.
    const int cid = blk - 64;                 // [0,16)
    const int t4  = (cid * 256 + tid) * 4;
    const int n   = t4 & 255;
    const int k8  = t4 >> 8;
    float4 rr[8];
    #pragma unroll
    for (int kk = 0; kk < 8; ++kk)
      rr[kk] = *(const float4*)(wo + (size_t)(k8 * 8 + kk) * QS + n);
    const int kc = k8 >> 2, qq = k8 & 3;
    #pragma unroll
    for (int nn = 0; nn < 4; ++nn) {
      const int nc = n + nn;
      const int l  = (nc & 15) + 16 * qq;
      const size_t off = ((size_t)((nc >> 4) * 16 + kc) * 64 + l) * 8;
      bf16x8 hv, lv;
      #pragma unroll
      for (int kk = 0; kk < 8; ++kk) {
        const float v = (nn == 0) ? rr[kk].x : (nn == 1) ? rr[kk].y
                      : (nn == 2) ? rr[kk].z : rr[kk].w;
        const __bf16 h16 = (__bf16)v;
        hv[kk] = h16;
        lv[kk] = (__bf16)(v - (float)h16);
      }
      *(bf16x8*)(WOBH + off) = hv;
      *(bf16x8*)(WOBL + off) = lv;
    }
  }
}

// ---------------- kernel 1: QKV projections, MFMA ----------------
// grid 256 (b*64 + nblk), 512 thr (8 waves), 16 x-rows per block, all 3 proj.
// stage1: x(16x256) @ w1cat(256x128) -> tb32 (SiLU on [40,80)).
// stage2: tb32 @ w2(p) (K=64 pad) -> qb/kb/vb LDS -> R15 write phases.
__global__ __launch_bounds__(512) void qkv_kernel(
    const float* __restrict__ x,
    const __hip_bfloat16* __restrict__ W1BH, const __hip_bfloat16* __restrict__ W1BL,
    const __hip_bfloat16* __restrict__ W2BH, const __hip_bfloat16* __restrict__ W2BL,
    __hip_bfloat16* __restrict__ Qg, __hip_bfloat16* __restrict__ KSg,
    __hip_bfloat16* __restrict__ VSg)
{
  const int tid  = threadIdx.x;
  const int b    = blockIdx.x >> 6;
  const int nblk = blockIdx.x & 63;
  const int n0   = nblk << 4;
  const int wave = tid >> 6;
  const int lane = tid & 63;
  const int m    = lane & 15;     // A-frag row / D col-part
  const int q    = lane >> 4;     // k-subgroup / D row-quad

  __shared__ __align__(16) float xs[16][260];
  __shared__ __align__(16) float tb32[16][140];
  __shared__ __align__(16) __hip_bfloat16 qb[8320];    // [16][520]
  __shared__ __align__(16) __hip_bfloat16 kb[8320];    // [16][520]
  __shared__ __align__(16) __hip_bfloat16 vb[10240];   // [512][20]

  // stage x tile: 1024 float4 tasks, 2 per thread
  #pragma unroll
  for (int j = 0; j < 2; ++j) {
    const int i  = tid + j * 512;
    const int r  = i >> 6;
    const int c4 = (i & 63) << 2;
    *(float4*)(&xs[r][c4]) =
        *(const float4*)(x + ((size_t)b * NSEQ + n0 + r) * QS + c4);
  }
  __syncthreads();

  // ---- build x A-frags (hi/lo), all 8 K-chunks: row m, k = kc*32+q*8+j
  bf16x8 xh[8], xl[8];
  #pragma unroll
  for (int kc = 0; kc < 8; ++kc) {
    const float4 f0 = *(const float4*)(&xs[m][kc * 32 + q * 8]);
    const float4 f1 = *(const float4*)(&xs[m][kc * 32 + q * 8 + 4]);
    float v[8] = {f0.x, f0.y, f0.z, f0.w, f1.x, f1.y, f1.z, f1.w};
    #pragma unroll
    for (int j = 0; j < 8; ++j) {
      const __bf16 h16 = (__bf16)v[j];
      xh[kc][j] = h16;
      xl[kc][j] = (__bf16)(v[j] - (float)h16);
    }
  }

  // ---- stage 1: wave w owns cat n-tile w. 24 MFMA (3-chain hi/lo).
  {
    floatx4 hh = (floatx4){0.f, 0.f, 0.f, 0.f};
    floatx4 hl = (floatx4){0.f, 0.f, 0.f, 0.f};
    floatx4 lh = (floatx4){0.f, 0.f, 0.f, 0.f};
    const __hip_bfloat16* w1h = W1BH + ((size_t)wave * 8 * 64 + lane) * 8;
    const __hip_bfloat16* w1l = W1BL + ((size_t)wave * 8 * 64 + lane) * 8;
    #pragma unroll
    for (int kc = 0; kc < 8; ++kc) {
      const bf16x8 bh = *(const bf16x8*)(w1h + kc * 512);
      const bf16x8 bl = *(const bf16x8*)(w1l + kc * 512);
      hh = __builtin_amdgcn_mfma_f32_16x16x32_bf16(xh[kc], bh, hh, 0, 0, 0);
      hl = __builtin_amdgcn_mfma_f32_16x16x32_bf16(xh[kc], bl, hl, 0, 0, 0);
      lh = __builtin_amdgcn_mfma_f32_16x16x32_bf16(xl[kc], bh, lh, 0, 0, 0);
    }
    const int n1 = wave * 16 + m;   // cat col (D col = lane&15)
    #pragma unroll
    for (int r = 0; r < 4; ++r) {
      float d = (hh[r] + hl[r]) + lh[r];
      if (n1 >= 40 && n1 < 80) d = d / (1.f + __expf(-d));   // SiLU on K path
      tb32[q * 4 + r][n1] = d;       // D row = q*4+r
    }
  }
  __syncthreads();

  // ---- stage 2: per proj p (compile-time), wave covers n-tiles wave*4+i.
  #pragma unroll
  for (int p = 0; p < 3; ++p) {
    // A2 frags from tb32 (hi/lo). kc=0: k=q*8+j (<32, real).
    // kc=1: k=32+q*8+j, real only for q==0 (k 32..39); else zero.
    bf16x8 a2h[2], a2l[2];
    {
      const float4 g0 = *(const float4*)(&tb32[m][p * 40 + q * 8]);
      const float4 g1 = *(const float4*)(&tb32[m][p * 40 + q * 8 + 4]);
      float v[8] = {g0.x, g0.y, g0.z, g0.w, g1.x, g1.y, g1.z, g1.w};
      #pragma unroll
      for (int j = 0; j < 8; ++j) {
        const __bf16 h16 = (__bf16)v[j];
        a2h[0][j] = h16;
        a2l[0][j] = (__bf16)(v[j] - (float)h16);
      }
    }
    if (q == 0) {
      const float4 g0 = *(const float4*)(&tb32[m][p * 40 + 32]);
      const float4 g1 = *(const float4*)(&tb32[m][p * 40 + 36]);
      float v[8] = {g0.x, g0.y, g0.z, g0.w, g1.x, g1.y, g1.z, g1.w};
      #pragma unroll
      for (int j = 0; j < 8; ++j) {
        const __bf16 h16 = (__bf16)v[j];
        a2h[1][j] = h16;
        a2l[1][j] = (__bf16)(v[j] - (float)h16);
      }
    } else {
      #pragma unroll
      for (int j = 0; j < 8; ++j) { a2h[1][j] = (__bf16)0.f; a2l[1][j] = (__bf16)0.f; }
    }

    #pragma unroll
    for (int i = 0; i < 4; ++i) {
      const int nt = wave * 4 + i;
      floatx4 sHH = (floatx4){0.f, 0.f, 0.f, 0.f};
      floatx4 sHL = (floatx4){0.f, 0.f, 0.f, 0.f};
      floatx4 sLH = (floatx4){0.f, 0.f, 0.f, 0.f};
      #pragma unroll
      for (int kc = 0; kc < 2; ++kc) {
        const size_t boff = (((size_t)(p * 32 + nt) * 2 + kc) * 64 + lane) * 8;
        const bf16x8 bh = *(const bf16x8*)(W2BH + boff);
        const bf16x8 bl = *(const bf16x8*)(W2BL + boff);
        sHH = __builtin_amdgcn_mfma_f32_16x16x32_bf16(a2h[kc], bh, sHH, 0, 0, 0);
        sHL = __builtin_amdgcn_mfma_f32_16x16x32_bf16(a2h[kc], bl, sHL, 0, 0, 0);
        sLH = __builtin_amdgcn_mfma_f32_16x16x32_bf16(a2l[kc], bh, sLH, 0, 0, 0);
      }
      const int nn = nt * 16 + m;    // output col [0,512)
      #pragma unroll
      for (int r = 0; r < 4; ++r) {
        const int row = q * 4 + r;
        const float d = (sHH[r] + sHL[r]) + sLH[r];
        if (p == 0)      qb[row * 520 + nn] = __float2bfloat16(d * QSCALE);
        else if (p == 1) kb[row * 520 + nn] = __float2bfloat16(d);
        else             vb[nn * 20 + row]  = __float2bfloat16(d);
      }
    }
  }
  __syncthreads();

  // ---- Q write: 1024 float4 tasks, 2 per thread (R15-identical) ----
  #pragma unroll
  for (int j = 0; j < 2; ++j) {
    const int i  = tid + j * 512;
    const int h  = i >> 7;
    const int r  = (i >> 3) & 15;
    const int d8 = i & 7;
    *(float4*)(Qg + ((size_t)b * SEQ + h * NSEQ + n0 + r) * DH + d8 * 8) =
        *(const float4*)(&qb[r * 520 + h * 64 + d8 * 8]);
  }
  // ---- K_sw write: 1024 float4 tasks, 2 per thread (R15-identical) ----
  #pragma unroll
  for (int j = 0; j < 2; ++j) {
    const int i    = tid + j * 512;
    const int h    = i >> 7;
    const int ks2  = (i >> 6) & 1;
    const int quad = (i >> 4) & 3;
    const int r    = i & 15;
    const int ln   = quad * 16 + r;
    const size_t dst = (size_t)b * KVSW_BATCH
        + ((size_t)((h * 64 + nblk) * 2 + ks2) * 64 + ln) * 8;
    *(float4*)(KSg + dst) = *(const float4*)(&kb[r * 520 + h * 64 + ks2 * 32 + quad * 8]);
  }
  // ---- V_sw write: 2048 uint2 tasks, 4 per thread (R15-identical) ----
  {
    const int st  = nblk & 1;
    const int p32 = nblk >> 1;
    #pragma unroll
    for (int pass = 0; pass < 4; ++pass) {
      const int i   = tid + pass * 512;
      const int h   = i >> 8;
      const int dnt = (i >> 6) & 3;
      const int dm  = (i >> 2) & 15;
      const int rg  = i & 3;
      const int ln  = rg * 16 + dm;
      const size_t dst = (size_t)b * KVSW_BATCH
          + ((size_t)((h * 32 + p32) * 4 + dnt) * 64 + ln) * 8 + st * 4;
      *(uint2*)(VSg + dst) = *(const uint2*)(&vb[(h * 64 + dnt * 16 + dm) * 20 + rg * 4]);
    }
  }
}

// ---------------- kernel 2: attention, kv-split partial blocks (frozen R8-R13) ----------------
struct PairBuf {
  bf16x8 k[2][2];   // [strip][k-span]
  bf16x8 v[4];      // [d-tile]
};

__global__ __launch_bounds__(256, 3) void attn_kernel(
    const __hip_bfloat16* __restrict__ Qg,
    const __hip_bfloat16* __restrict__ KSg,
    const __hip_bfloat16* __restrict__ VSg,
    float* __restrict__ OPg,       // [2][B_][SEQ][DH]
    float* __restrict__ PSg)       // [2][B_][SEQ]
{
  __shared__ float Osh[4][16][68];
  __shared__ float psums[4][64];

  const int tid  = threadIdx.x;
  const int wave = tid >> 6;
  const int lane = tid & 63;
  const int lrow = lane & 15;
  const int quad = lane >> 4;

  const int xcd   = blockIdx.x & 7;
  const int idx   = blockIdx.x >> 3;       // [0,128)
  const int b     = xcd >> 1;
  const int half  = idx & 1;
  const int qtile = (xcd & 1) * 64 + (idx >> 1);
  const int qbase = qtile * 64;

  const __hip_bfloat16* Qb  = Qg + ((size_t)b * SEQ + qbase) * DH;
  const __hip_bfloat16* kp0 = KSg + (size_t)b * KVSW_BATCH + half * 262144
                              + (size_t)wave * 65536 + lane * 8;
  const __hip_bfloat16* vp0 = VSg + (size_t)b * KVSW_BATCH + half * 262144
                              + (size_t)wave * 65536 + lane * 8;

  bf16x8 qf[4][2];
  #pragma unroll
  for (int mt = 0; mt < 4; ++mt)
    #pragma unroll
    for (int s = 0; s < 2; ++s)
      qf[mt][s] = *(const bf16x8*)(Qb + (mt * 16 + lrow) * DH + s * 32 + quad * 8);

  floatx4 oacc[4][4];   // [mt][dnt] — 64 acc regs (unified budget)
  #pragma unroll
  for (int mt = 0; mt < 4; ++mt)
    #pragma unroll
    for (int dnt = 0; dnt < 4; ++dnt)
      oacc[mt][dnt] = (floatx4){0.f, 0.f, 0.f, 0.f};
  float psum[4] = {0.f, 0.f, 0.f, 0.f};

  #pragma unroll 2
  for (int pair = 0; pair < 32; ++pair) {
    PairBuf pb;
    const __hip_bfloat16* kp = kp0 + pair * 2048;
    pb.k[0][0] = *(const bf16x8*)(kp);
    pb.k[0][1] = *(const bf16x8*)(kp + 512);
    pb.k[1][0] = *(const bf16x8*)(kp + 1024);
    pb.k[1][1] = *(const bf16x8*)(kp + 1536);
    const __hip_bfloat16* vp = vp0 + pair * 2048;
    #pragma unroll
    for (int dnt = 0; dnt < 4; ++dnt)
      pb.v[dnt] = *(const bf16x8*)(vp + dnt * 512);

    #pragma unroll
    for (int mt = 0; mt < 4; ++mt) {
      floatx4 s0 = (floatx4){0.f, 0.f, 0.f, 0.f};
      floatx4 s1 = (floatx4){0.f, 0.f, 0.f, 0.f};
      s0 = __builtin_amdgcn_mfma_f32_16x16x32_bf16(pb.k[0][0], qf[mt][0], s0, 0, 0, 0);
      s0 = __builtin_amdgcn_mfma_f32_16x16x32_bf16(pb.k[0][1], qf[mt][1], s0, 0, 0, 0);
      s1 = __builtin_amdgcn_mfma_f32_16x16x32_bf16(pb.k[1][0], qf[mt][0], s1, 0, 0, 0);
      s1 = __builtin_amdgcn_mfma_f32_16x16x32_bf16(pb.k[1][1], qf[mt][1], s1, 0, 0, 0);
      float p[8];
      #pragma unroll
      for (int r = 0; r < 4; ++r) {
        p[r]     = __builtin_amdgcn_exp2f(s0[r]);
        p[4 + r] = __builtin_amdgcn_exp2f(s1[r]);
      }
      psum[mt] += ((p[0] + p[1]) + (p[2] + p[3])) + ((p[4] + p[5]) + (p[6] + p[7]));
      bf16x8 pa;
      #pragma unroll
      for (int j = 0; j < 8; ++j) pa[j] = (__bf16)p[j];
      #pragma unroll
      for (int dnt = 0; dnt < 4; ++dnt)
        oacc[mt][dnt] = __builtin_amdgcn_mfma_f32_16x16x32_bf16(pa, pb.v[dnt], oacc[mt][dnt], 0, 0, 0);
    }
  }

  #pragma unroll
  for (int mt = 0; mt < 4; ++mt) {
    float s = psum[mt];
    s += __shfl_xor(s, 16, 64);
    s += __shfl_xor(s, 32, 64);
    psum[mt] = s;
  }
  if (quad == 0) {
    #pragma unroll
    for (int mt = 0; mt < 4; ++mt)
      psums[wave][mt * 16 + lrow] = psum[mt];
  }

  const size_t opbase = ((size_t)half * B_ + b) * SEQ + qbase;

  #pragma unroll
  for (int mt = 0; mt < 4; ++mt) {
    #pragma unroll
    for (int dnt = 0; dnt < 4; ++dnt)
      #pragma unroll
      for (int r = 0; r < 4; ++r)
        Osh[wave][quad * 4 + r][dnt * 16 + lrow] = oacc[mt][dnt][r];
    __syncthreads();

    {
      const int q16 = tid >> 4;
      const int d0  = (tid & 15) * 4;
      float4 a0 = *(const float4*)(&Osh[0][q16][d0]);
      float4 a1 = *(const float4*)(&Osh[1][q16][d0]);
      float4 a2 = *(const float4*)(&Osh[2][q16][d0]);
      float4 a3 = *(const float4*)(&Osh[3][q16][d0]);
      float4 res;
      res.x = (a0.x + a1.x) + (a2.x + a3.x);
      res.y = (a0.y + a1.y) + (a2.y + a3.y);
      res.z = (a0.z + a1.z) + (a2.z + a3.z);
      res.w = (a0.w + a1.w) + (a2.w + a3.w);
      *(float4*)(OPg + (opbase + mt * 16 + q16) * DH + d0) = res;
    }
    if (mt == 0 && tid < 64) {
      const float tot = (psums[0][tid] + psums[1][tid]) + (psums[2][tid] + psums[3][tid]);
      PSg[opbase + tid] = tot;
    }
    __syncthreads();
  }
}

// ---------------- kernel 3: out = merge(Opart)/denom @ wo + bo — MFMA (frozen R16) ----------------
__global__ __launch_bounds__(256, 1) void out_kernel(
    const float* __restrict__ OPg, const float* __restrict__ PSg,
    const __hip_bfloat16* __restrict__ WOBH, const __hip_bfloat16* __restrict__ WOBL,
    const float* __restrict__ bo, float* __restrict__ out)
{
  __shared__ __align__(16) __hip_bfloat16 apH[8192];   // [kc][lane][8]
  __shared__ __align__(16) __hip_bfloat16 apL[8192];
  __shared__ float invs[16][8];

  const int tid  = threadIdx.x;
  const int b    = blockIdx.x >> 6;
  const int n0   = (blockIdx.x & 63) << 4;
  const int lane = tid & 63;
  const int wave = tid >> 6;

  if (tid < 128) {
    const int r = tid >> 3, h = tid & 7;
    const size_t row = (size_t)b * SEQ + h * NSEQ + n0 + r;
    invs[r][h] = 1.0f / (PSg[row] + PSg[(size_t)B_ * SEQ + row]);
  }
  __syncthreads();

  // ---- phase 1: merge halves + normalize -> hi/lo A-frag pack.
  {
    const int m   = tid & 15;
    const int q   = (tid >> 4) & 3;
    const int kc0 = tid >> 6;
    #pragma unroll
    for (int pss = 0; pss < 4; ++pss) {
      const int kc = kc0 + pss * 4;
      const int h  = kc >> 1;
      const int dh = (q + 4 * (kc & 1)) * 8;
      const size_t idx = (((size_t)b * H_ + h) * NSEQ + n0 + m) * DH + dh;
      const float4 a0 = *(const float4*)(OPg + idx);
      const float4 a1 = *(const float4*)(OPg + idx + 4);
      const float4 b0 = *(const float4*)(OPg + OPHALF + idx);
      const float4 b1 = *(const float4*)(OPg + OPHALF + idx + 4);
      const float inv = invs[m][h];
      float v[8];
      v[0] = (a0.x + b0.x) * inv; v[1] = (a0.y + b0.y) * inv;
      v[2] = (a0.z + b0.z) * inv; v[3] = (a0.w + b0.w) * inv;
      v[4] = (a1.x + b1.x) * inv; v[5] = (a1.y + b1.y) * inv;
      v[6] = (a1.z + b1.z) * inv; v[7] = (a1.w + b1.w) * inv;
      bf16x8 hv, lv;
      #pragma unroll
      for (int j = 0; j < 8; ++j) {
        const __bf16 h16 = (__bf16)v[j];
        hv[j] = h16;
        lv[j] = (__bf16)(v[j] - (float)h16);
      }
      const int off = (kc * 64 + (m + 16 * q)) * 8;
      *(bf16x8*)(apH + off) = hv;
      *(bf16x8*)(apL + off) = lv;
    }
  }
  __syncthreads();

  // ---- phase 2: MFMA. A-frags (all 16 kc, hi+lo) -> 128 VGPR, B from L2.
  bf16x8 ah[16], al[16];
  #pragma unroll
  for (int kc = 0; kc < 16; ++kc) {
    ah[kc] = *(const bf16x8*)(apH + (kc * 64 + lane) * 8);
    al[kc] = *(const bf16x8*)(apL + (kc * 64 + lane) * 8);
  }

  const int colq = lane & 15;
  const int quad = lane >> 4;

  #pragma unroll
  for (int nt4 = 0; nt4 < 4; ++nt4) {
    const int nt = nt4 * 4 + wave;
    const __hip_bfloat16* wbh = WOBH + ((size_t)nt * 16 * 64 + lane) * 8;
    const __hip_bfloat16* wbl = WOBL + ((size_t)nt * 16 * 64 + lane) * 8;
    floatx4 aHH = (floatx4){0.f, 0.f, 0.f, 0.f};
    floatx4 aHL = (floatx4){0.f, 0.f, 0.f, 0.f};
    floatx4 aLH = (floatx4){0.f, 0.f, 0.f, 0.f};
    #pragma unroll
    for (int kg = 0; kg < 4; ++kg) {
      bf16x8 bh[4], bl[4];
      #pragma unroll
      for (int j = 0; j < 4; ++j) {
        bh[j] = *(const bf16x8*)(wbh + (kg * 4 + j) * 512);
        bl[j] = *(const bf16x8*)(wbl + (kg * 4 + j) * 512);
      }
      #pragma unroll
      for (int j = 0; j < 4; ++j) {
        const int kc = kg * 4 + j;
        aHH = __builtin_amdgcn_mfma_f32_16x16x32_bf16(ah[kc], bh[j], aHH, 0, 0, 0);
        aHL = __builtin_amdgcn_mfma_f32_16x16x32_bf16(ah[kc], bl[j], aHL, 0, 0, 0);
        aLH = __builtin_amdgcn_mfma_f32_16x16x32_bf16(al[kc], bh[j], aLH, 0, 0, 0);
      }
    }
    const int n  = nt * 16 + colq;
    const float bv = bo[n];
    #pragma unroll
    for (int r = 0; r < 4; ++r) {
      const int mm = quad * 4 + r;
      out[((size_t)b * NSEQ + n0 + mm) * QS + n] =
          ((aHH[r] + aHL[r]) + aLH[r]) + bv;
    }
  }
}

extern "C" void kernel_launch(void* const* d_in, const int* in_sizes, int n_in,
                              void* d_out, int out_size, void* d_ws, size_t ws_size,
                              hipStream_t stream) {
  const float* x   = (const float*)d_in[0];
  const float* wq1 = (const float*)d_in[1];
  const float* wq2 = (const float*)d_in[2];
  const float* wk1 = (const float*)d_in[3];
  const float* wk2 = (const float*)d_in[4];
  const float* wv1 = (const float*)d_in[5];
  const float* wv2 = (const float*)d_in[6];
  const float* wo  = (const float*)d_in[7];
  const float* bo  = (const float*)d_in[8];
  float* out = (float*)d_out;

  __hip_bfloat16* Qg  = (__hip_bfloat16*)d_ws;
  __hip_bfloat16* KSg = Qg + (size_t)B_ * SEQ * DH;
  __hip_bfloat16* VSg = KSg + (size_t)B_ * KVSW_BATCH;
  float*          OPg = (float*)(VSg + (size_t)B_ * KVSW_BATCH);   // [2][B_][SEQ][DH]
  float*          PSg = OPg + 2 * (size_t)B_ * SEQ * DH;           // [2][B_][SEQ]
  __hip_bfloat16* WOBH = (__hip_bfloat16*)(PSg + 2 * (size_t)B_ * SEQ);
  __hip_bfloat16* WOBL = WOBH + (size_t)INNER * QS;                // 131072
  __hip_bfloat16* W1BH = WOBL + (size_t)INNER * QS;
  __hip_bfloat16* W1BL = W1BH + 32768;
  __hip_bfloat16* W2BH = W1BL + 32768;
  __hip_bfloat16* W2BL = W2BH + 98304;

  conv_kernel<<<80, 256, 0, stream>>>(wq1, wk1, wv1, wq2, wk2, wv2, wo,
                                      W1BH, W1BL, W2BH, W2BL, WOBH, WOBL);
  qkv_kernel<<<256, 512, 0, stream>>>(x, W1BH, W1BL, W2BH, W2BL, Qg, KSg, VSg);
  attn_kernel<<<1024, 256, 0, stream>>>(Qg, KSg, VSg, OPg, PSg);
  out_kernel<<<256, 256, 0, stream>>>(OPg, PSg, WOBH, WOBL, bo, out);
}